// Round 2
// baseline (3695.002 us; speedup 1.0000x reference)
//
#include <hip/hip_runtime.h>
#include <hip/hip_bf16.h>
#include <stdint.h>
#include <math.h>

typedef unsigned long long ull;

// ============ prep: fold BN scale into weights + transpose to [CIN*9][COUT] ============
__global__ __launch_bounds__(256)
void wfold(const float* __restrict__ w, const float* __restrict__ g,
           const float* __restrict__ v, float* __restrict__ Wt, int COUT, int K9) {
  __shared__ float t[64][65];
  const int r0 = blockIdx.x * 64, oc0 = blockIdx.y * 64;
  const int tid = threadIdx.x;
#pragma unroll
  for (int i = 0; i < 16; ++i) {
    int idx = tid + i * 256;
    int ocl = idx >> 6, rl = idx & 63;
    float s = g[oc0 + ocl] / sqrtf(v[oc0 + ocl] + 1e-5f);
    t[ocl][rl] = w[(size_t)(oc0 + ocl) * K9 + r0 + rl] * s;
  }
  __syncthreads();
#pragma unroll
  for (int i = 0; i < 16; ++i) {
    int idx = tid + i * 256;
    int rl = idx >> 6, ocl = idx & 63;
    Wt[(size_t)(r0 + rl) * COUT + oc0 + ocl] = t[ocl][rl];
  }
}

__global__ __launch_bounds__(256)
void bfold(const float* __restrict__ b, const float* __restrict__ g,
           const float* __restrict__ be, const float* __restrict__ m,
           const float* __restrict__ v, float* __restrict__ bias2, int n) {
  int i = blockIdx.x * 256 + threadIdx.x;
  if (i < n) bias2[i] = (b[i] - m[i]) * (g[i] / sqrtf(v[i] + 1e-5f)) + be[i];
}

// ============ Conv3x3 SAME + folded-BN + LeakyReLU (fp32, VALU) ============
// Block 256 thr: tile = 128 linear px x 128 couts. Thread: 2 px-quads x 8 couts.
// X LDS: [8ic][NR][WP=W+4] padded rows (2 zero cols left, >=2 right) -> each
// 3-tap window = 2 aligned ds_read_b128. W LDS: [72][128] staged contiguously
// from pre-transposed Wt. All staging writes are tid-contiguous (conflict-free).
template<int CIN, int COUT, int H, int W, int NR>
__global__ __launch_bounds__(256, 3)
void conv3x3_f32(const float* __restrict__ x, const float* __restrict__ Wt,
                 const float* __restrict__ bias2, float* __restrict__ y) {
  constexpr int HW = H * W;
  constexpr int WP = W + 4;
  constexpr int WPH = WP / 2;
  __shared__ float Xs[8 * NR * WP];
  __shared__ float Ws[72 * 128];
  const int tid = threadIdx.x;
  const int gx = tid & 15, cy = tid >> 4;
  const int pt = blockIdx.x, ct = blockIdx.y, b = blockIdx.z;
  const int p0 = pt * 128;
  const int rbase = p0 / W;
  const int pA = p0 + gx * 4, pB = pA + 64;
  const int lrA = min(pA / W - rbase, NR - 3), csA = pA % W;
  const int lrB = min(pB / W - rbase, NR - 3), csB = pB % W;
  const float* xb = x + (size_t)b * CIN * HW;

  float acc[2][8][4] = {};

  for (int ic0 = 0; ic0 < CIN; ic0 += 8) {
    __syncthreads();
    // ---- stage X: 8 ch x NR rows x WP cols (float2 units, contiguous writes)
    for (int u = tid; u < 8 * NR * WPH; u += 256) {
      int ic = u / (NR * WPH), rem = u % (NR * WPH);
      int rho = rem / WPH, c2 = rem % WPH;
      int row = rbase - 1 + rho, c = c2 * 2 - 2;
      float2 val = make_float2(0.f, 0.f);
      if (row >= 0 && row < H && c >= 0 && c < W)
        val = *(const float2*)&xb[(size_t)(ic0 + ic) * HW + row * W + c];
      *(float2*)&Xs[(ic * NR + rho) * WP + c2 * 2] = val;
    }
    // ---- stage W slab: 72 rows x 128 couts (float4 units, contiguous writes)
    {
      const float* wsrc = Wt + (size_t)(ic0 * 9) * COUT + ct * 128;
#pragma unroll
      for (int i = 0; i < 9; ++i) {
        int u = tid + i * 256;
        int rrow = u >> 5, c4 = (u & 31) * 4;
        *(float4*)&Ws[rrow * 128 + c4] = *(const float4*)&wsrc[(size_t)rrow * COUT + c4];
      }
    }
    __syncthreads();
#pragma unroll 2
    for (int ic = 0; ic < 8; ++ic) {
      const int xb0 = ic * NR * WP;
      const int wb0 = ic * 9 * 128 + cy * 8;
#pragma unroll
      for (int dy = 0; dy < 3; ++dy) {
        float4 fa = *(const float4*)&Xs[xb0 + (lrA + dy) * WP + csA];
        float4 fb = *(const float4*)&Xs[xb0 + (lrA + dy) * WP + csA + 4];
        float4 ha = *(const float4*)&Xs[xb0 + (lrB + dy) * WP + csB];
        float4 hb = *(const float4*)&Xs[xb0 + (lrB + dy) * WP + csB + 4];
        float fv[8] = {fa.x, fa.y, fa.z, fa.w, fb.x, fb.y, fb.z, fb.w};
        float hv[8] = {ha.x, ha.y, ha.z, ha.w, hb.x, hb.y, hb.z, hb.w};
#pragma unroll
        for (int dx = 0; dx < 3; ++dx) {
          const float* wr = &Ws[wb0 + (dy * 3 + dx) * 128];
          float4 w0 = *(const float4*)wr;
          float4 w1 = *(const float4*)(wr + 4);
          float wv[8] = {w0.x, w0.y, w0.z, w0.w, w1.x, w1.y, w1.z, w1.w};
#pragma unroll
          for (int c = 0; c < 8; ++c) {
#pragma unroll
            for (int j = 0; j < 4; ++j) {
              acc[0][c][j] = fmaf(wv[c], fv[1 + dx + j], acc[0][c][j]);
              acc[1][c][j] = fmaf(wv[c], hv[1 + dx + j], acc[1][c][j]);
            }
          }
        }
      }
    }
  }
  // ---- epilogue: +bias2, leaky relu, store
#pragma unroll
  for (int c = 0; c < 8; ++c) {
    int oc = ct * 128 + cy * 8 + c;
    float bs = bias2[oc];
    if (pA < HW) {
      float4 o;
      o.x = acc[0][c][0] + bs; o.y = acc[0][c][1] + bs;
      o.z = acc[0][c][2] + bs; o.w = acc[0][c][3] + bs;
      o.x = o.x > 0.f ? o.x : 0.1f * o.x; o.y = o.y > 0.f ? o.y : 0.1f * o.y;
      o.z = o.z > 0.f ? o.z : 0.1f * o.z; o.w = o.w > 0.f ? o.w : 0.1f * o.w;
      *(float4*)&y[((size_t)(b * COUT + oc)) * HW + pA] = o;
    }
    if (pB < HW) {
      float4 o;
      o.x = acc[1][c][0] + bs; o.y = acc[1][c][1] + bs;
      o.z = acc[1][c][2] + bs; o.w = acc[1][c][3] + bs;
      o.x = o.x > 0.f ? o.x : 0.1f * o.x; o.y = o.y > 0.f ? o.y : 0.1f * o.y;
      o.z = o.z > 0.f ? o.z : 0.1f * o.z; o.w = o.w > 0.f ? o.w : 0.1f * o.w;
      *(float4*)&y[((size_t)(b * COUT + oc)) * HW + pB] = o;
    }
  }
}

// ================= fused 1x1 conv (255 couts) + decode =================
template<int CIN>
__global__ __launch_bounds__(256)
void head1x1_decode(const float* __restrict__ act, const float* __restrict__ pw,
                    const float* __restrict__ pb,
                    int HW, int Wl, float strd, int P0,
                    float aw0, float ah0, float aw1, float ah1, float aw2, float ah2,
                    float* __restrict__ out, float* __restrict__ boxes,
                    float* __restrict__ scb, int* __restrict__ clsb) {
  __shared__ union {
    struct { float a[8][64]; float w[8][256]; } s;
    float pred[64 * 256];
  } u;
  const int pt = blockIdx.x, b = blockIdx.y;
  const int p0 = pt * 64;
  const int tid = threadIdx.x;
  const int og = tid & 15;
  const int pg = tid >> 4;

  float acc[4][16];
#pragma unroll
  for (int pi = 0; pi < 4; ++pi)
#pragma unroll
    for (int k = 0; k < 16; ++k) acc[pi][k] = 0.f;

  for (int ic0 = 0; ic0 < CIN; ic0 += 8) {
    __syncthreads();
    for (int idx = tid; idx < 512; idx += 256) {
      int ic = idx >> 6, px = idx & 63;
      int p = p0 + px;
      u.s.a[ic][px] = (p < HW) ? act[(size_t)(b * CIN + ic0 + ic) * HW + p] : 0.f;
    }
    for (int idx = tid; idx < 2048; idx += 256) {
      int oc = idx >> 3, ic = idx & 7;
      u.s.w[ic][oc] = (oc < 255) ? pw[(size_t)oc * CIN + ic0 + ic] : 0.f;
    }
    __syncthreads();
#pragma unroll 1
    for (int ic = 0; ic < 8; ++ic) {
      float4 a4 = *(const float4*)&u.s.a[ic][pg * 4];
      const float4* wrow = (const float4*)&u.s.w[ic][og * 16];
      float4 w0 = wrow[0], w1 = wrow[1], w2 = wrow[2], w3 = wrow[3];
      float av[4] = {a4.x, a4.y, a4.z, a4.w};
      float wv[16] = {w0.x, w0.y, w0.z, w0.w, w1.x, w1.y, w1.z, w1.w,
                      w2.x, w2.y, w2.z, w2.w, w3.x, w3.y, w3.z, w3.w};
#pragma unroll
      for (int pi = 0; pi < 4; ++pi)
#pragma unroll
        for (int k = 0; k < 16; ++k)
          acc[pi][k] = fmaf(av[pi], wv[k], acc[pi][k]);
    }
  }
  __syncthreads();
  float pbv[16];
#pragma unroll
  for (int k = 0; k < 16; ++k) {
    int oc = og * 16 + k;
    pbv[k] = (oc < 255) ? pb[oc] : 0.f;
  }
#pragma unroll
  for (int pi = 0; pi < 4; ++pi) {
    int px = pg * 4 + pi;
    int swz = px & 28;
#pragma unroll
    for (int k4 = 0; k4 < 4; ++k4) {
      float4 v;
      v.x = acc[pi][k4 * 4 + 0] + pbv[k4 * 4 + 0];
      v.y = acc[pi][k4 * 4 + 1] + pbv[k4 * 4 + 1];
      v.z = acc[pi][k4 * 4 + 2] + pbv[k4 * 4 + 2];
      v.w = acc[pi][k4 * 4 + 3] + pbv[k4 * 4 + 3];
      *(float4*)&u.pred[px * 256 + (((og * 16 + k4 * 4) ^ swz))] = v;
    }
  }
  __syncthreads();
  if (tid < 192) {
    const int px = tid & 63, a = tid >> 6;
    const int p = p0 + px;
    if (p < HW) {
      const int swz = px & 28;
      const float* pr = &u.pred[px * 256];
#define RD(ch) pr[(ch) ^ swz]
      float conf = RD(a);
      int ch0 = 3 + 80 * a;
      float m = -1e30f; int ci = 0;
      for (int i = 0; i < 80; ++i) {
        float v = RD(ch0 + i);
        if (v > m) { m = v; ci = i; }
      }
      float ssum = 0.f;
      for (int i = 0; i < 80; ++i) ssum += expf(RD(ch0 + i) - m);
      float sig = 1.f / (1.f + expf(-conf));
      float sc = sig / ssum;
      float tx = RD(243 + 4 * a), ty = RD(244 + 4 * a);
      float tw = RD(245 + 4 * a), th = RD(246 + 4 * a);
#undef RD
      float gxx = (float)(p % Wl), gy = (float)(p / Wl);
      float aw = (a == 0) ? aw0 : ((a == 1) ? aw1 : aw2);
      float ah = (a == 0) ? ah0 : ((a == 1) ? ah1 : ah2);
      float cx = (1.f / (1.f + expf(-tx)) + gxx) * strd;
      float cy2 = (1.f / (1.f + expf(-ty)) + gy) * strd;
      float bw = expf(tw) * aw, bh = expf(th) * ah;
      float x1 = fminf(fmaxf((cx - bw * 0.5f) / 640.f, 0.f), 1.f);
      float y1 = fminf(fmaxf((cy2 - bh * 0.5f) / 640.f, 0.f), 1.f);
      float x2 = fminf(fmaxf((cx + bw * 0.5f) / 640.f, 0.f), 1.f);
      float y2 = fminf(fmaxf((cy2 + bh * 0.5f) / 640.f, 0.f), 1.f);
      int n = (P0 + p) * 3 + a;
      size_t gg = (size_t)b * 25200 + n;
      out[gg * 5 + 0] = (x1 + x2) * 0.5f * 640.f;
      out[gg * 5 + 1] = (y1 + y2) * 0.5f * 640.f;
      out[gg * 5 + 2] = (x2 - x1) * 640.f;
      out[gg * 5 + 3] = (y2 - y1) * 640.f;
      out[gg * 5 + 4] = sc;
      out[(size_t)8 * 25200 * 5 + gg] = (float)ci;
      out[(size_t)8 * 25200 * 6 + gg] = 0.f;
      boxes[gg * 4 + 0] = x1; boxes[gg * 4 + 1] = y1;
      boxes[gg * 4 + 2] = x2; boxes[gg * 4 + 3] = y2;
      scb[gg] = sc; clsb[gg] = ci;
    }
  }
}

// ================= top-k (compact + bitonic) =================
__global__ __launch_bounds__(256)
void topk_sort(const float* __restrict__ scb, const float* __restrict__ boxes,
               const int* __restrict__ clsb,
               int* __restrict__ tidx, int* __restrict__ tval, float* __restrict__ tbox) {
  __shared__ ull keys[4096];
  __shared__ int cnt;
  const int b = blockIdx.x, tid = threadIdx.x;
  if (tid == 0) cnt = 0;
  __syncthreads();
  for (int n = tid; n < 25200; n += 256) {
    float s = scb[(size_t)b * 25200 + n];
    if (s >= 0.3f) {
      int p = atomicAdd(&cnt, 1);
      if (p < 4096)
        keys[p] = ((ull)__float_as_uint(s) << 32) | (ull)(0xFFFFFFFFu - (unsigned)n);
    }
  }
  __syncthreads();
  int c = min(cnt, 4096);
  int P2 = 1024;
  while (P2 < c) P2 <<= 1;
  for (int i = c + tid; i < P2; i += 256) keys[i] = 0ull;
  __syncthreads();
  for (int len = 2; len <= P2; len <<= 1) {
    for (int j = len >> 1; j > 0; j >>= 1) {
      for (int x = tid; x < P2; x += 256) {
        int y = x ^ j;
        if (y > x) {
          ull a = keys[x], bb = keys[y];
          bool up = (x & len) == 0;
          if (up ? (a < bb) : (a > bb)) { keys[x] = bb; keys[y] = a; }
        }
      }
      __syncthreads();
    }
  }
  for (int i = tid; i < 1000; i += 256) {
    ull k = keys[i];
    int valid = (k != 0ull) ? 1 : 0;
    int n = valid ? (int)(0xFFFFFFFFu - (unsigned)(k & 0xFFFFFFFFull)) : 0;
    float cls = (float)clsb[(size_t)b * 25200 + n];
    float off = cls * 4.0f;
    const float* bp = &boxes[((size_t)b * 25200 + n) * 4];
    tidx[b * 1000 + i] = n;
    tval[b * 1000 + i] = valid;
    tbox[(b * 1000 + i) * 4 + 0] = bp[0] + off;
    tbox[(b * 1000 + i) * 4 + 1] = bp[1] + off;
    tbox[(b * 1000 + i) * 4 + 2] = bp[2] + off;
    tbox[(b * 1000 + i) * 4 + 3] = bp[3] + off;
  }
}

// ================= pairwise suppression bitmasks =================
__global__ __launch_bounds__(1024)
void supmask(const float* __restrict__ tbox, ull* __restrict__ sup) {
  __shared__ float4 bx[1000];
  __shared__ float ar[1000];
  const int b = blockIdx.x, tid = threadIdx.x;
  for (int i = tid; i < 1000; i += 1024) {
    float4 v = *(const float4*)&tbox[((size_t)b * 1000 + i) * 4];
    bx[i] = v;
    ar[i] = (v.z - v.x) * (v.w - v.y);
  }
  __syncthreads();
  if (tid < 1000) {
    float4 bi = bx[tid];
    float ai = ar[tid];
    ull w = 0;
    for (int j = 0; j < 1000; ++j) {
      float4 bj = bx[j];
      float xx1 = fmaxf(bi.x, bj.x), yy1 = fmaxf(bi.y, bj.y);
      float xx2 = fminf(bi.z, bj.z), yy2 = fminf(bi.w, bj.w);
      float inter = fmaxf(1e-28f, xx2 - xx1) * fmaxf(1e-28f, yy2 - yy1);
      float iou = inter / (ai + ar[j] - inter);
      if (iou > 0.5f) w |= 1ull << (j & 63);
      if ((j & 63) == 63) { sup[((size_t)b * 1000 + tid) * 16 + (j >> 6)] = w; w = 0; }
    }
    sup[((size_t)b * 1000 + tid) * 16 + 15] = w;
  }
}

// ================= greedy NMS (serial, ballot-driven) =================
__global__ __launch_bounds__(64)
void nms_kernel(const ull* __restrict__ sup, const int* __restrict__ tval,
                const int* __restrict__ tidx, float* __restrict__ keep_out) {
  const int b = blockIdx.x, lane = threadIdx.x;
  __shared__ ull slds[64][17];
  ull keepw = 0;
  for (int ch = 0; ch < 16; ++ch) {
    int i0 = ch * 64;
    int nIn = min(64, 1000 - i0);
    for (int k = 0; k < 16; ++k) {
      int linear = k * 64 + lane;
      int row = linear >> 4, w = linear & 15;
      slds[row][w] = (row < nIn) ? sup[((size_t)b * 1000 + i0 + row) * 16 + w] : 0ull;
    }
    int myvalid = (lane < nIn) ? tval[b * 1000 + i0 + lane] : 0;
    int myidx = (lane < nIn) ? tidx[b * 1000 + i0 + lane] : 0;
    __syncthreads();
    for (int li = 0; li < nIn; ++li) {
      ull m = (lane < 16) ? (keepw & slds[li][lane]) : 0ull;
      bool sup_any = __any(m != 0ull);
      int v = __shfl(myvalid, li);
      bool keep_i = v && !sup_any;
      if (keep_i) {
        if (lane == ch) keepw |= 1ull << li;
        if (lane == li) keep_out[(size_t)b * 25200 + myidx] = 1.0f;
      }
    }
    __syncthreads();
  }
}

// ================= launch =================
extern "C" void kernel_launch(void* const* d_in, const int* in_sizes, int n_in,
                              void* d_out, int out_size, void* d_ws, size_t ws_size,
                              hipStream_t stream) {
  const float* p3 = (const float*)d_in[0];
  const float* p4 = (const float*)d_in[1];
  const float* p5 = (const float*)d_in[2];
  auto L = [&](int lvl, int k) { return (const float*)d_in[3 + lvl * 8 + k]; };
  float* out = (float*)d_out;
  char* ws = (char*)d_ws;
  float* act = (float*)ws;                 size_t o = (size_t)13107200 * 4;
  float* Wt1 = (float*)(ws + o);           o += (size_t)294912 * 4;
  float* Wt2 = (float*)(ws + o);           o += (size_t)1179648 * 4;
  float* Wt3 = (float*)(ws + o);           o += (size_t)4718592 * 4;
  float* bias2 = (float*)(ws + o);         o += 2048 * 4;        // 256|512|1024 packed
  float* boxes = (float*)(ws + o);         o += (size_t)806400 * 4;
  float* scb = (float*)(ws + o);           o += (size_t)201600 * 4;
  int* clsb = (int*)(ws + o);              o += (size_t)201600 * 4;
  int* tidx = (int*)(ws + o);              o += 8000 * 4;
  int* tval = (int*)(ws + o);              o += 8000 * 4;
  float* tbox = (float*)(ws + o);          o += 32000 * 4;
  ull* sup = (ull*)(ws + o);               o += (size_t)128000 * 8;
  float* b2_1 = bias2, *b2_2 = bias2 + 256, *b2_3 = bias2 + 768;

  // ---- prep: fold BN + transpose weights
  wfold<<<dim3(18, 4), 256, 0, stream>>>(L(0, 0), L(0, 2), L(0, 5), Wt1, 256, 1152);
  wfold<<<dim3(36, 8), 256, 0, stream>>>(L(1, 0), L(1, 2), L(1, 5), Wt2, 512, 2304);
  wfold<<<dim3(72, 16), 256, 0, stream>>>(L(2, 0), L(2, 2), L(2, 5), Wt3, 1024, 4608);
  bfold<<<1, 256, 0, stream>>>(L(0, 1), L(0, 2), L(0, 3), L(0, 4), L(0, 5), b2_1, 256);
  bfold<<<2, 256, 0, stream>>>(L(1, 1), L(1, 2), L(1, 3), L(1, 4), L(1, 5), b2_2, 512);
  bfold<<<4, 256, 0, stream>>>(L(2, 1), L(2, 2), L(2, 3), L(2, 4), L(2, 5), b2_3, 1024);

  // ---- level 1: 128->256, 80x80
  conv3x3_f32<128, 256, 80, 80, 5><<<dim3(50, 2, 8), 256, 0, stream>>>(p3, Wt1, b2_1, act);
  head1x1_decode<256><<<dim3(100, 8), 256, 0, stream>>>(
      act, L(0, 6), L(0, 7), 6400, 80, 8.f, 0,
      32.64f, 47.68f, 50.24f, 108.16f, 126.72f, 96.32f, out, boxes, scb, clsb);
  // ---- level 2: 256->512, 40x40
  conv3x3_f32<256, 512, 40, 40, 6><<<dim3(13, 4, 8), 256, 0, stream>>>(p4, Wt2, b2_2, act);
  head1x1_decode<512><<<dim3(25, 8), 256, 0, stream>>>(
      act, L(1, 6), L(1, 7), 1600, 40, 16.f, 6400,
      78.4f, 201.92f, 178.24f, 178.56f, 129.6f, 294.72f, out, boxes, scb, clsb);
  // ---- level 3: 512->1024, 20x20
  conv3x3_f32<512, 1024, 20, 20, 10><<<dim3(4, 8, 8), 256, 0, stream>>>(p5, Wt3, b2_3, act);
  head1x1_decode<1024><<<dim3(7, 8), 256, 0, stream>>>(
      act, L(2, 6), L(2, 7), 400, 20, 32.f, 8000,
      331.84f, 194.56f, 227.84f, 325.76f, 365.44f, 358.72f, out, boxes, scb, clsb);
  // ---- NMS pipeline
  topk_sort<<<8, 256, 0, stream>>>(scb, boxes, clsb, tidx, tval, tbox);
  supmask<<<8, 1024, 0, stream>>>(tbox, sup);
  nms_kernel<<<8, 64, 0, stream>>>(sup, tval, tidx, out + (size_t)8 * 25200 * 6);
}

// Round 4
// 1860.259 us; speedup vs baseline: 1.9863x; 1.9863x over previous
//
#include <hip/hip_runtime.h>
#include <hip/hip_bf16.h>
#include <stdint.h>
#include <math.h>

typedef unsigned long long ull;
typedef __attribute__((ext_vector_type(8))) _Float16 f16x8;
typedef __attribute__((ext_vector_type(4))) float f32x4;

// f16 split: v ~= hi + lo*2^-11, both normal-range f16 (lo pre-scaled by 2^11)
__device__ __forceinline__ void f16_split(float v, short& hi, short& lo) {
  _Float16 h = (_Float16)v;                  // v_cvt_f16_f32, RNE
  float r = v - (float)h;
  _Float16 l = (_Float16)(r * 2048.f);
  hi = __builtin_bit_cast(short, h);
  lo = __builtin_bit_cast(short, l);
}
__device__ __forceinline__ unsigned pk2(short a, short b) {
  return (unsigned)(unsigned short)a | ((unsigned)(unsigned short)b << 16);
}

// ======== prep: x fp32 NCHW -> XC f16 [B][HW][hi:CIN | lo2048:CIN] ========
__global__ __launch_bounds__(256)
void xprep(const float* __restrict__ x, short* __restrict__ XC, int HW, int CIN) {
  __shared__ float T[32 * 132];
  const int p0 = blockIdx.x * 128, c0 = blockIdx.y * 32, b = blockIdx.z;
  const int tid = threadIdx.x;
#pragma unroll
  for (int i = 0; i < 16; ++i) {
    int u = tid + i * 256;
    int ch = u >> 7, px = u & 127;
    int gp = p0 + px;
    float v = 0.f;
    if (gp < HW) v = x[((size_t)b * CIN + c0 + ch) * HW + gp];
    T[ch * 132 + px] = v;
  }
  __syncthreads();
  const int px = tid & 127, half = tid >> 7;
  const int gp = p0 + px;
  if (gp < HW) {
    short h[16], l[16];
#pragma unroll
    for (int k = 0; k < 16; ++k)
      f16_split(T[(half * 16 + k) * 132 + px], h[k], l[k]);
    short* dh = XC + ((size_t)b * HW + gp) * 2 * CIN + c0 + half * 16;
    short* dl = dh + CIN;
    int4 a, bq;
    a.x = pk2(h[0], h[1]); a.y = pk2(h[2], h[3]); a.z = pk2(h[4], h[5]); a.w = pk2(h[6], h[7]);
    bq.x = pk2(h[8], h[9]); bq.y = pk2(h[10], h[11]); bq.z = pk2(h[12], h[13]); bq.w = pk2(h[14], h[15]);
    *(int4*)dh = a; *(int4*)(dh + 8) = bq;
    a.x = pk2(l[0], l[1]); a.y = pk2(l[2], l[3]); a.z = pk2(l[4], l[5]); a.w = pk2(l[6], l[7]);
    bq.x = pk2(l[8], l[9]); bq.y = pk2(l[10], l[11]); bq.z = pk2(l[12], l[13]); bq.w = pk2(l[14], l[15]);
    *(int4*)dl = a; *(int4*)(dl + 8) = bq;
  }
}

// ======== prep: weights -> BN-folded f16 hi/lo MFMA B-fragments ========
// WF layout (shorts): [kc*9+t][og][hl][lane][8j], frag=512 shorts, og-stride=1024.
__global__ __launch_bounds__(256)
void wprep(const float* __restrict__ w, const float* __restrict__ g,
           const float* __restrict__ v, short* __restrict__ WF, int CIN, int lgNOG) {
  const int NOG = 1 << lgNOG;
  int e = blockIdx.x * 256 + threadIdx.x;   // over (kc, t, og, lane)
  int lane = e & 63;
  int og = (e >> 6) & (NOG - 1);
  int r = e >> (6 + lgNOG);
  int t = r % 9, kc = r / 9;
  int oc = og * 16 + (lane & 15);
  int icb = kc * 32 + (lane >> 4) * 8;
  float s = g[oc] / sqrtf(v[oc] + 1e-5f);
  short h[8], l[8];
#pragma unroll
  for (int j = 0; j < 8; ++j) {
    float val = w[((size_t)oc * CIN + icb + j) * 9 + t] * s;
    f16_split(val, h[j], l[j]);
  }
  size_t base = ((size_t)(kc * 9 + t) * NOG + og) * 1024 + lane * 8;
  int4 a;
  a.x = pk2(h[0], h[1]); a.y = pk2(h[2], h[3]); a.z = pk2(h[4], h[5]); a.w = pk2(h[6], h[7]);
  *(int4*)&WF[base] = a;
  a.x = pk2(l[0], l[1]); a.y = pk2(l[2], l[3]); a.z = pk2(l[4], l[5]); a.w = pk2(l[6], l[7]);
  *(int4*)&WF[base + 512] = a;
}

__global__ __launch_bounds__(256)
void bfold(const float* __restrict__ b, const float* __restrict__ g,
           const float* __restrict__ be, const float* __restrict__ m,
           const float* __restrict__ v, float* __restrict__ bias2, int n) {
  int i = blockIdx.x * 256 + threadIdx.x;
  if (i < n) bias2[i] = (b[i] - m[i]) * (g[i] / sqrtf(v[i] + 1e-5f)) + be[i];
}

// ======== Conv3x3 SAME + folded-BN + LeakyReLU via f16-split MFMA ========
// Block 256 = 4 waves. Tile: 320 px (ROWS*W) x OG*16 oc. Waves M-split (80 px).
// acc0 += xh*wh ; acc1 += xh*(wl*2^11) + (xl*2^11)*wh ; out = acc0 + acc1/2048.
template<int CIN, int COUT, int H, int W, int ROWS, int OG>
__global__ __launch_bounds__(256, 2)
void conv3x3_mfma(const short* __restrict__ XC, const short* __restrict__ WF,
                  const float* __restrict__ bias2, float* __restrict__ act) {
  constexpr int HW = H * W, WP = W + 2, NROW = ROWS + 2, NOGT = COUT / 16;
  constexpr int BSH = OG * 1024;
  __shared__ short Xs[NROW * WP * 64];       // px-stride 64sh, 16B granules XOR-swz
  __shared__ short Bs[2][BSH];
  const int tid = threadIdx.x, lane = tid & 63, wave = tid >> 6;
  const int tile = blockIdx.x, octile = blockIdx.y, b = blockIdx.z;
  const int r0 = tile * ROWS;
  const int tile_px0 = r0 * W;
  const int kgrp = lane >> 4, lm = lane & 15;
  int Pbase[5];
#pragma unroll
  for (int m = 0; m < 5; ++m) {
    int pl = wave * 80 + m * 16 + lm;
    Pbase[m] = (pl / W) * WP + (pl % W);
  }
  f32x4 acc0[5][OG], acc1[5][OG];
#pragma unroll
  for (int m = 0; m < 5; ++m)
#pragma unroll
    for (int og = 0; og < OG; ++og) {
      acc0[m][og] = (f32x4){0.f, 0.f, 0.f, 0.f};
      acc1[m][og] = (f32x4){0.f, 0.f, 0.f, 0.f};
    }

  const size_t xcb = (size_t)b * HW * 2 * CIN;
  const int og0 = octile * OG;

  // pre-zero halo cols (col 0 and W+1), all staged rows, both halves
  for (int u = tid; u < NROW * 2 * 8; u += 256) {
    int sub = u & 7, rc = u >> 3;
    int pxi = (rc >> 1) * WP + ((rc & 1) ? (W + 1) : 0);
    *(int4*)&Xs[pxi * 64 + ((sub ^ (pxi & 7)) << 3)] = make_int4(0, 0, 0, 0);
  }

  for (int kc = 0; kc < CIN / 32; ++kc) {
    // ---- stage X (16B granules, XOR-swizzled within each px's 128B)
    for (int g0 = tid; g0 < NROW * W * 8; g0 += 256) {
      int sub = g0 & 7, px = g0 >> 3;
      int rr = px / W, col = px % W;
      int gr = r0 - 1 + rr;
      int pxi = rr * WP + col + 1;
      int dst = pxi * 64 + ((sub ^ (pxi & 7)) << 3);
      if (gr >= 0 && gr < H) {
        const short* src = XC + xcb + (size_t)(gr * W + col) * 2 * CIN +
                           ((sub & 4) ? CIN : 0) + kc * 32 + (sub & 3) * 8;
        *(int4*)&Xs[dst] = *(const int4*)src;
      } else {
        *(int4*)&Xs[dst] = make_int4(0, 0, 0, 0);
      }
    }
    // ---- stage B tap0 -> Bs[0] (linear copy)
    {
      const short* src = WF + ((size_t)(kc * 9 + 0) * NOGT + og0) * 1024 + tid * (BSH / 256);
      *(int4*)&Bs[0][tid * (BSH / 256)] = *(const int4*)src;
      if constexpr (OG == 4)
        *(int4*)&Bs[0][tid * 16 + 8] = *(const int4*)(src + 8);
    }
    __syncthreads();
#pragma unroll 1
    for (int t = 0; t < 9; ++t) {
      int4 r0v, r1v;
      if (t < 8) {   // T14: issue next-tap loads early
        const short* src = WF + ((size_t)(kc * 9 + t + 1) * NOGT + og0) * 1024 + tid * (BSH / 256);
        r0v = *(const int4*)src;
        if constexpr (OG == 4) r1v = *(const int4*)(src + 8);
      }
      const short* bs = Bs[t & 1];
      f16x8 bh[OG], bl[OG];
#pragma unroll
      for (int og = 0; og < OG; ++og) {
        bh[og] = *(const f16x8*)&bs[(og * 2 + 0) * 512 + lane * 8];
        bl[og] = *(const f16x8*)&bs[(og * 2 + 1) * 512 + lane * 8];
      }
      const int tp = (t / 3) * WP + (t % 3);
#pragma unroll
      for (int m = 0; m < 5; ++m) {
        int P = Pbase[m] + tp;
        int base = P * 64, ph = P & 7;
        f16x8 ah = *(const f16x8*)&Xs[base + ((kgrp ^ ph) << 3)];
        f16x8 al = *(const f16x8*)&Xs[base + (((kgrp + 4) ^ ph) << 3)];
#pragma unroll
        for (int og = 0; og < OG; ++og) {
          acc0[m][og] = __builtin_amdgcn_mfma_f32_16x16x32_f16(ah, bh[og], acc0[m][og], 0, 0, 0);
          acc1[m][og] = __builtin_amdgcn_mfma_f32_16x16x32_f16(ah, bl[og], acc1[m][og], 0, 0, 0);
          acc1[m][og] = __builtin_amdgcn_mfma_f32_16x16x32_f16(al, bh[og], acc1[m][og], 0, 0, 0);
        }
      }
      if (t < 8) {
        *(int4*)&Bs[(t + 1) & 1][tid * (BSH / 256)] = r0v;
        if constexpr (OG == 4)
          *(int4*)&Bs[(t + 1) & 1][tid * 16 + 8] = r1v;
      }
      __syncthreads();
    }
  }
  // ---- epilogue: combine hi/lo acc, +bias, leaky relu, fp32 NCHW store
  float bv[OG];
#pragma unroll
  for (int og = 0; og < OG; ++og) bv[og] = bias2[octile * OG * 16 + og * 16 + lm];
#pragma unroll
  for (int m = 0; m < 5; ++m) {
    int p = tile_px0 + wave * 80 + m * 16 + kgrp * 4;
    if (p < HW) {
#pragma unroll
      for (int og = 0; og < OG; ++og) {
        int oc = octile * OG * 16 + og * 16 + lm;
        f32x4 v0 = acc0[m][og], v1 = acc1[m][og];
        float4 o;
        o.x = fmaf(v1[0], 4.8828125e-4f, v0[0]) + bv[og];
        o.y = fmaf(v1[1], 4.8828125e-4f, v0[1]) + bv[og];
        o.z = fmaf(v1[2], 4.8828125e-4f, v0[2]) + bv[og];
        o.w = fmaf(v1[3], 4.8828125e-4f, v0[3]) + bv[og];
        o.x = o.x > 0.f ? o.x : 0.1f * o.x;
        o.y = o.y > 0.f ? o.y : 0.1f * o.y;
        o.z = o.z > 0.f ? o.z : 0.1f * o.z;
        o.w = o.w > 0.f ? o.w : 0.1f * o.w;
        *(float4*)&act[((size_t)(b * COUT + oc)) * HW + p] = o;
      }
    }
  }
}

// ================= fused 1x1 conv (255 couts) + decode =================
template<int CIN>
__global__ __launch_bounds__(256)
void head1x1_decode(const float* __restrict__ act, const float* __restrict__ pw,
                    const float* __restrict__ pb,
                    int HW, int Wl, float strd, int P0,
                    float aw0, float ah0, float aw1, float ah1, float aw2, float ah2,
                    float* __restrict__ out, float* __restrict__ boxes,
                    float* __restrict__ scb, int* __restrict__ clsb) {
  __shared__ union {
    struct { float a[8][64]; float w[8][256]; } s;
    float pred[64 * 256];
  } u;
  const int pt = blockIdx.x, b = blockIdx.y;
  const int p0 = pt * 64;
  const int tid = threadIdx.x;
  const int og = tid & 15;
  const int pg = tid >> 4;

  float acc[4][16];
#pragma unroll
  for (int pi = 0; pi < 4; ++pi)
#pragma unroll
    for (int k = 0; k < 16; ++k) acc[pi][k] = 0.f;

  for (int ic0 = 0; ic0 < CIN; ic0 += 8) {
    __syncthreads();
    for (int idx = tid; idx < 512; idx += 256) {
      int ic = idx >> 6, px = idx & 63;
      int p = p0 + px;
      u.s.a[ic][px] = (p < HW) ? act[(size_t)(b * CIN + ic0 + ic) * HW + p] : 0.f;
    }
    for (int idx = tid; idx < 2048; idx += 256) {
      int oc = idx >> 3, ic = idx & 7;
      u.s.w[ic][oc] = (oc < 255) ? pw[(size_t)oc * CIN + ic0 + ic] : 0.f;
    }
    __syncthreads();
#pragma unroll 1
    for (int ic = 0; ic < 8; ++ic) {
      float4 a4 = *(const float4*)&u.s.a[ic][pg * 4];
      const float4* wrow = (const float4*)&u.s.w[ic][og * 16];
      float4 w0 = wrow[0], w1 = wrow[1], w2 = wrow[2], w3 = wrow[3];
      float av[4] = {a4.x, a4.y, a4.z, a4.w};
      float wv[16] = {w0.x, w0.y, w0.z, w0.w, w1.x, w1.y, w1.z, w1.w,
                      w2.x, w2.y, w2.z, w2.w, w3.x, w3.y, w3.z, w3.w};
#pragma unroll
      for (int pi = 0; pi < 4; ++pi)
#pragma unroll
        for (int k = 0; k < 16; ++k)
          acc[pi][k] = fmaf(av[pi], wv[k], acc[pi][k]);
    }
  }
  __syncthreads();
  float pbv[16];
#pragma unroll
  for (int k = 0; k < 16; ++k) {
    int oc = og * 16 + k;
    pbv[k] = (oc < 255) ? pb[oc] : 0.f;
  }
#pragma unroll
  for (int pi = 0; pi < 4; ++pi) {
    int px = pg * 4 + pi;
    int swz = px & 28;
#pragma unroll
    for (int k4 = 0; k4 < 4; ++k4) {
      float4 v;
      v.x = acc[pi][k4 * 4 + 0] + pbv[k4 * 4 + 0];
      v.y = acc[pi][k4 * 4 + 1] + pbv[k4 * 4 + 1];
      v.z = acc[pi][k4 * 4 + 2] + pbv[k4 * 4 + 2];
      v.w = acc[pi][k4 * 4 + 3] + pbv[k4 * 4 + 3];
      *(float4*)&u.pred[px * 256 + (((og * 16 + k4 * 4) ^ swz))] = v;
    }
  }
  __syncthreads();
  if (tid < 192) {
    const int px = tid & 63, a = tid >> 6;
    const int p = p0 + px;
    if (p < HW) {
      const int swz = px & 28;
      const float* pr = &u.pred[px * 256];
#define RD(ch) pr[(ch) ^ swz]
      float conf = RD(a);
      int ch0 = 3 + 80 * a;
      float m = -1e30f; int ci = 0;
      for (int i = 0; i < 80; ++i) {
        float v = RD(ch0 + i);
        if (v > m) { m = v; ci = i; }
      }
      float ssum = 0.f;
      for (int i = 0; i < 80; ++i) ssum += expf(RD(ch0 + i) - m);
      float sig = 1.f / (1.f + expf(-conf));
      float sc = sig / ssum;
      float tx = RD(243 + 4 * a), ty = RD(244 + 4 * a);
      float tw = RD(245 + 4 * a), th = RD(246 + 4 * a);
#undef RD
      float gxx = (float)(p % Wl), gy = (float)(p / Wl);
      float aw = (a == 0) ? aw0 : ((a == 1) ? aw1 : aw2);
      float ah = (a == 0) ? ah0 : ((a == 1) ? ah1 : ah2);
      float cx = (1.f / (1.f + expf(-tx)) + gxx) * strd;
      float cy2 = (1.f / (1.f + expf(-ty)) + gy) * strd;
      float bw = expf(tw) * aw, bh = expf(th) * ah;
      float x1 = fminf(fmaxf((cx - bw * 0.5f) / 640.f, 0.f), 1.f);
      float y1 = fminf(fmaxf((cy2 - bh * 0.5f) / 640.f, 0.f), 1.f);
      float x2 = fminf(fmaxf((cx + bw * 0.5f) / 640.f, 0.f), 1.f);
      float y2 = fminf(fmaxf((cy2 + bh * 0.5f) / 640.f, 0.f), 1.f);
      int n = (P0 + p) * 3 + a;
      size_t gg = (size_t)b * 25200 + n;
      out[gg * 5 + 0] = (x1 + x2) * 0.5f * 640.f;
      out[gg * 5 + 1] = (y1 + y2) * 0.5f * 640.f;
      out[gg * 5 + 2] = (x2 - x1) * 640.f;
      out[gg * 5 + 3] = (y2 - y1) * 640.f;
      out[gg * 5 + 4] = sc;
      out[(size_t)8 * 25200 * 5 + gg] = (float)ci;
      out[(size_t)8 * 25200 * 6 + gg] = 0.f;
      boxes[gg * 4 + 0] = x1; boxes[gg * 4 + 1] = y1;
      boxes[gg * 4 + 2] = x2; boxes[gg * 4 + 3] = y2;
      scb[gg] = sc; clsb[gg] = ci;
    }
  }
}

// ================= top-k (compact + bitonic) =================
__global__ __launch_bounds__(256)
void topk_sort(const float* __restrict__ scb, const float* __restrict__ boxes,
               const int* __restrict__ clsb,
               int* __restrict__ tidx, int* __restrict__ tval, float* __restrict__ tbox) {
  __shared__ ull keys[4096];
  __shared__ int cnt;
  const int b = blockIdx.x, tid = threadIdx.x;
  if (tid == 0) cnt = 0;
  __syncthreads();
  for (int n = tid; n < 25200; n += 256) {
    float s = scb[(size_t)b * 25200 + n];
    if (s >= 0.3f) {
      int p = atomicAdd(&cnt, 1);
      if (p < 4096)
        keys[p] = ((ull)__float_as_uint(s) << 32) | (ull)(0xFFFFFFFFu - (unsigned)n);
    }
  }
  __syncthreads();
  int c = min(cnt, 4096);
  int P2 = 1024;
  while (P2 < c) P2 <<= 1;
  for (int i = c + tid; i < P2; i += 256) keys[i] = 0ull;
  __syncthreads();
  for (int len = 2; len <= P2; len <<= 1) {
    for (int j = len >> 1; j > 0; j >>= 1) {
      for (int x = tid; x < P2; x += 256) {
        int y = x ^ j;
        if (y > x) {
          ull a = keys[x], bb = keys[y];
          bool up = (x & len) == 0;
          if (up ? (a < bb) : (a > bb)) { keys[x] = bb; keys[y] = a; }
        }
      }
      __syncthreads();
    }
  }
  for (int i = tid; i < 1000; i += 256) {
    ull k = keys[i];
    int valid = (k != 0ull) ? 1 : 0;
    int n = valid ? (int)(0xFFFFFFFFu - (unsigned)(k & 0xFFFFFFFFull)) : 0;
    float cls = (float)clsb[(size_t)b * 25200 + n];
    float off = cls * 4.0f;
    const float* bp = &boxes[((size_t)b * 25200 + n) * 4];
    tidx[b * 1000 + i] = n;
    tval[b * 1000 + i] = valid;
    tbox[(b * 1000 + i) * 4 + 0] = bp[0] + off;
    tbox[(b * 1000 + i) * 4 + 1] = bp[1] + off;
    tbox[(b * 1000 + i) * 4 + 2] = bp[2] + off;
    tbox[(b * 1000 + i) * 4 + 3] = bp[3] + off;
  }
}

// ================= pairwise suppression bitmasks =================
__global__ __launch_bounds__(1024)
void supmask(const float* __restrict__ tbox, ull* __restrict__ sup) {
  __shared__ float4 bx[1000];
  __shared__ float ar[1000];
  const int b = blockIdx.x, tid = threadIdx.x;
  for (int i = tid; i < 1000; i += 1024) {
    float4 v = *(const float4*)&tbox[((size_t)b * 1000 + i) * 4];
    bx[i] = v;
    ar[i] = (v.z - v.x) * (v.w - v.y);
  }
  __syncthreads();
  if (tid < 1000) {
    float4 bi = bx[tid];
    float ai = ar[tid];
    ull w = 0;
    for (int j = 0; j < 1000; ++j) {
      float4 bj = bx[j];
      float xx1 = fmaxf(bi.x, bj.x), yy1 = fmaxf(bi.y, bj.y);
      float xx2 = fminf(bi.z, bj.z), yy2 = fminf(bi.w, bj.w);
      float inter = fmaxf(1e-28f, xx2 - xx1) * fmaxf(1e-28f, yy2 - yy1);
      float iou = inter / (ai + ar[j] - inter);
      if (iou > 0.5f) w |= 1ull << (j & 63);
      if ((j & 63) == 63) { sup[((size_t)b * 1000 + tid) * 16 + (j >> 6)] = w; w = 0; }
    }
    sup[((size_t)b * 1000 + tid) * 16 + 15] = w;
  }
}

// ================= greedy NMS (serial, ballot-driven) =================
__global__ __launch_bounds__(64)
void nms_kernel(const ull* __restrict__ sup, const int* __restrict__ tval,
                const int* __restrict__ tidx, float* __restrict__ keep_out) {
  const int b = blockIdx.x, lane = threadIdx.x;
  __shared__ ull slds[64][17];
  ull keepw = 0;
  for (int ch = 0; ch < 16; ++ch) {
    int i0 = ch * 64;
    int nIn = min(64, 1000 - i0);
    for (int k = 0; k < 16; ++k) {
      int linear = k * 64 + lane;
      int row = linear >> 4, w = linear & 15;
      slds[row][w] = (row < nIn) ? sup[((size_t)b * 1000 + i0 + row) * 16 + w] : 0ull;
    }
    int myvalid = (lane < nIn) ? tval[b * 1000 + i0 + lane] : 0;
    int myidx = (lane < nIn) ? tidx[b * 1000 + i0 + lane] : 0;
    __syncthreads();
    for (int li = 0; li < nIn; ++li) {
      ull m = (lane < 16) ? (keepw & slds[li][lane]) : 0ull;
      bool sup_any = __any(m != 0ull);
      int v = __shfl(myvalid, li);
      bool keep_i = v && !sup_any;
      if (keep_i) {
        if (lane == ch) keepw |= 1ull << li;
        if (lane == li) keep_out[(size_t)b * 25200 + myidx] = 1.0f;
      }
    }
    __syncthreads();
  }
}

// ================= launch =================
extern "C" void kernel_launch(void* const* d_in, const int* in_sizes, int n_in,
                              void* d_out, int out_size, void* d_ws, size_t ws_size,
                              hipStream_t stream) {
  const float* p3 = (const float*)d_in[0];
  const float* p4 = (const float*)d_in[1];
  const float* p5 = (const float*)d_in[2];
  auto L = [&](int lvl, int k) { return (const float*)d_in[3 + lvl * 8 + k]; };
  float* out = (float*)d_out;
  char* ws = (char*)d_ws;
  size_t o = 0;
  float* act = (float*)(ws + o);   o += (size_t)13107200 * 4;   // fp32 NCHW
  short* XC  = (short*)(ws + o);   o += (size_t)13107200 * 2;
  short* WF  = (short*)(ws + o);   o += (size_t)9437184 * 2;
  float* bias2 = (float*)(ws + o); o += 2048 * 4;
  float* boxes = (float*)(ws + o); o += (size_t)806400 * 4;
  float* scb = (float*)(ws + o);   o += (size_t)201600 * 4;
  int* clsb = (int*)(ws + o);      o += (size_t)201600 * 4;
  int* tidx = (int*)(ws + o);      o += 8000 * 4;
  int* tval = (int*)(ws + o);      o += 8000 * 4;
  float* tbox = (float*)(ws + o);  o += 32000 * 4;
  ull* sup = (ull*)(ws + o);       o += (size_t)128000 * 8;
  float* b2_1 = bias2, *b2_2 = bias2 + 256, *b2_3 = bias2 + 768;

  bfold<<<1, 256, 0, stream>>>(L(0, 1), L(0, 2), L(0, 3), L(0, 4), L(0, 5), b2_1, 256);
  bfold<<<2, 256, 0, stream>>>(L(1, 1), L(1, 2), L(1, 3), L(1, 4), L(1, 5), b2_2, 512);
  bfold<<<4, 256, 0, stream>>>(L(2, 1), L(2, 2), L(2, 3), L(2, 4), L(2, 5), b2_3, 1024);

  // ---- level 1: 128->256, 80x80
  wprep<<<144, 256, 0, stream>>>(L(0, 0), L(0, 2), L(0, 5), WF, 128, 4);
  xprep<<<dim3(50, 4, 8), 256, 0, stream>>>(p3, XC, 6400, 128);
  conv3x3_mfma<128, 256, 80, 80, 4, 4><<<dim3(20, 4, 8), 256, 0, stream>>>(XC, WF, b2_1, act);
  head1x1_decode<256><<<dim3(100, 8), 256, 0, stream>>>(
      act, L(0, 6), L(0, 7), 6400, 80, 8.f, 0,
      32.64f, 47.68f, 50.24f, 108.16f, 126.72f, 96.32f, out, boxes, scb, clsb);
  // ---- level 2: 256->512, 40x40
  wprep<<<576, 256, 0, stream>>>(L(1, 0), L(1, 2), L(1, 5), WF, 256, 5);
  xprep<<<dim3(13, 8, 8), 256, 0, stream>>>(p4, XC, 1600, 256);
  conv3x3_mfma<256, 512, 40, 40, 8, 4><<<dim3(5, 8, 8), 256, 0, stream>>>(XC, WF, b2_2, act);
  head1x1_decode<512><<<dim3(25, 8), 256, 0, stream>>>(
      act, L(1, 6), L(1, 7), 1600, 40, 16.f, 6400,
      78.4f, 201.92f, 178.24f, 178.56f, 129.6f, 294.72f, out, boxes, scb, clsb);
  // ---- level 3: 512->1024, 20x20  (OG=2 -> 512 blocks, 2/CU)
  wprep<<<2304, 256, 0, stream>>>(L(2, 0), L(2, 2), L(2, 5), WF, 512, 6);
  xprep<<<dim3(4, 16, 8), 256, 0, stream>>>(p5, XC, 400, 512);
  conv3x3_mfma<512, 1024, 20, 20, 16, 2><<<dim3(2, 32, 8), 256, 0, stream>>>(XC, WF, b2_3, act);
  head1x1_decode<1024><<<dim3(7, 8), 256, 0, stream>>>(
      act, L(2, 6), L(2, 7), 400, 20, 32.f, 8000,
      331.84f, 194.56f, 227.84f, 325.76f, 365.44f, 358.72f, out, boxes, scb, clsb);
  // ---- NMS pipeline
  topk_sort<<<8, 256, 0, stream>>>(scb, boxes, clsb, tidx, tval, tbox);
  supmask<<<8, 1024, 0, stream>>>(tbox, sup);
  nms_kernel<<<8, 64, 0, stream>>>(sup, tval, tidx, out + (size_t)8 * 25200 * 6);
}

// Round 6
// 1188.194 us; speedup vs baseline: 3.1098x; 1.5656x over previous
//
#include <hip/hip_runtime.h>
#include <hip/hip_bf16.h>
#include <stdint.h>
#include <math.h>

typedef unsigned long long ull;
typedef __attribute__((ext_vector_type(8))) _Float16 f16x8;
typedef __attribute__((ext_vector_type(4))) float f32x4;

// f16 split: v ~= hi + lo*2^-11, lo pre-scaled by 2^11 (keeps lo normal-range)
__device__ __forceinline__ void f16_split(float v, short& hi, short& lo) {
  _Float16 h = (_Float16)v;
  float r = v - (float)h;
  _Float16 l = (_Float16)(r * 2048.f);
  hi = __builtin_bit_cast(short, h);
  lo = __builtin_bit_cast(short, l);
}
__device__ __forceinline__ unsigned pk2(short a, short b) {
  return (unsigned)(unsigned short)a | ((unsigned)(unsigned short)b << 16);
}

// ======== prep: x fp32 NCHW -> XC f16 [B][HW][hi:CIN | lo2048:CIN] ========
__global__ __launch_bounds__(256)
void xprep(const float* __restrict__ x, short* __restrict__ XC, int HW, int CIN) {
  __shared__ float T[32 * 132];
  const int p0 = blockIdx.x * 128, c0 = blockIdx.y * 32, b = blockIdx.z;
  const int tid = threadIdx.x;
#pragma unroll
  for (int i = 0; i < 16; ++i) {
    int u = tid + i * 256;
    int ch = u >> 7, px = u & 127;
    int gp = p0 + px;
    float v = 0.f;
    if (gp < HW) v = x[((size_t)b * CIN + c0 + ch) * HW + gp];
    T[ch * 132 + px] = v;
  }
  __syncthreads();
  const int px = tid & 127, half = tid >> 7;
  const int gp = p0 + px;
  if (gp < HW) {
    short h[16], l[16];
#pragma unroll
    for (int k = 0; k < 16; ++k)
      f16_split(T[(half * 16 + k) * 132 + px], h[k], l[k]);
    short* dh = XC + ((size_t)b * HW + gp) * 2 * CIN + c0 + half * 16;
    short* dl = dh + CIN;
    int4 a, bq;
    a.x = pk2(h[0], h[1]); a.y = pk2(h[2], h[3]); a.z = pk2(h[4], h[5]); a.w = pk2(h[6], h[7]);
    bq.x = pk2(h[8], h[9]); bq.y = pk2(h[10], h[11]); bq.z = pk2(h[12], h[13]); bq.w = pk2(h[14], h[15]);
    *(int4*)dh = a; *(int4*)(dh + 8) = bq;
    a.x = pk2(l[0], l[1]); a.y = pk2(l[2], l[3]); a.z = pk2(l[4], l[5]); a.w = pk2(l[6], l[7]);
    bq.x = pk2(l[8], l[9]); bq.y = pk2(l[10], l[11]); bq.z = pk2(l[12], l[13]); bq.w = pk2(l[14], l[15]);
    *(int4*)dl = a; *(int4*)(dl + 8) = bq;
  }
}

// ======== prep: conv weights -> BN-folded f16 hi/lo MFMA fragments ========
// WF layout (shorts): [kc*9+t][og][hl][lane][8j]
__global__ __launch_bounds__(256)
void wprep(const float* __restrict__ w, const float* __restrict__ g,
           const float* __restrict__ v, short* __restrict__ WF, int CIN, int lgNOG) {
  const int NOG = 1 << lgNOG;
  int e = blockIdx.x * 256 + threadIdx.x;
  int lane = e & 63;
  int og = (e >> 6) & (NOG - 1);
  int r = e >> (6 + lgNOG);
  int t = r % 9, kc = r / 9;
  int oc = og * 16 + (lane & 15);
  int icb = kc * 32 + (lane >> 4) * 8;
  float s = g[oc] / sqrtf(v[oc] + 1e-5f);
  short h[8], l[8];
#pragma unroll
  for (int j = 0; j < 8; ++j) {
    float val = w[((size_t)oc * CIN + icb + j) * 9 + t] * s;
    f16_split(val, h[j], l[j]);
  }
  size_t base = ((size_t)(kc * 9 + t) * NOG + og) * 1024 + lane * 8;
  int4 a;
  a.x = pk2(h[0], h[1]); a.y = pk2(h[2], h[3]); a.z = pk2(h[4], h[5]); a.w = pk2(h[6], h[7]);
  *(int4*)&WF[base] = a;
  a.x = pk2(l[0], l[1]); a.y = pk2(l[2], l[3]); a.z = pk2(l[4], l[5]); a.w = pk2(l[6], l[7]);
  *(int4*)&WF[base + 512] = a;
}

// ======== prep: head 1x1 weights -> f16 hi/lo fragments ========
// WH layout (shorts): [kc][og(16)][hl][lane][8j] ; oc>=255 zero-padded
__global__ __launch_bounds__(256)
void hwprep(const float* __restrict__ pw, short* __restrict__ WH, int CIN) {
  int e = blockIdx.x * 256 + threadIdx.x;   // (kc, og, lane)
  int lane = e & 63;
  int og = (e >> 6) & 15;
  int kc = e >> 10;
  int oc = og * 16 + (lane & 15);
  int ic0 = kc * 32 + (lane >> 4) * 8;
  short h[8], l[8];
#pragma unroll
  for (int j = 0; j < 8; ++j) {
    float val = (oc < 255) ? pw[(size_t)oc * CIN + ic0 + j] : 0.f;
    f16_split(val, h[j], l[j]);
  }
  size_t base = ((size_t)(kc * 16 + og) * 2) * 512 + lane * 8;
  int4 a;
  a.x = pk2(h[0], h[1]); a.y = pk2(h[2], h[3]); a.z = pk2(h[4], h[5]); a.w = pk2(h[6], h[7]);
  *(int4*)&WH[base] = a;
  a.x = pk2(l[0], l[1]); a.y = pk2(l[2], l[3]); a.z = pk2(l[4], l[5]); a.w = pk2(l[6], l[7]);
  *(int4*)&WH[base + 512] = a;
}

__global__ __launch_bounds__(256)
void bfold(const float* __restrict__ b, const float* __restrict__ g,
           const float* __restrict__ be, const float* __restrict__ m,
           const float* __restrict__ v, float* __restrict__ bias2, int n) {
  int i = blockIdx.x * 256 + threadIdx.x;
  if (i < n) bias2[i] = (b[i] - m[i]) * (g[i] / sqrtf(v[i] + 1e-5f)) + be[i];
}

// ======== Conv3x3 SAME + folded-BN + LeakyReLU via f16-split MFMA ========
// Operand-swapped (W as A-operand): C col=px, row=oc -> epilogue writes
// ACT directly in NHWC f16 hi/lo format [B][HW][hi:COUT | lo2048:COUT].
template<int CIN, int COUT, int H, int W, int ROWS, int OG>
__global__ __launch_bounds__(256, 2)
void conv3x3_mfma(const short* __restrict__ XC, const short* __restrict__ WF,
                  const float* __restrict__ bias2, short* __restrict__ ACT) {
  constexpr int HW = H * W, WP = W + 2, NROW = ROWS + 2, NOGT = COUT / 16;
  constexpr int BSH = OG * 1024;
  __shared__ short Xs[NROW * WP * 64];
  __shared__ short Bs[2][BSH];
  const int tid = threadIdx.x, lane = tid & 63, wave = tid >> 6;
  const int tile = blockIdx.x, octile = blockIdx.y, b = blockIdx.z;
  const int r0 = tile * ROWS;
  const int tile_px0 = r0 * W;
  const int kgrp = lane >> 4, lm = lane & 15;
  int Pbase[5];
#pragma unroll
  for (int m = 0; m < 5; ++m) {
    int pl = wave * 80 + m * 16 + lm;
    Pbase[m] = (pl / W) * WP + (pl % W);
  }
  f32x4 acc0[5][OG], acc1[5][OG];
#pragma unroll
  for (int m = 0; m < 5; ++m)
#pragma unroll
    for (int og = 0; og < OG; ++og) {
      acc0[m][og] = (f32x4){0.f, 0.f, 0.f, 0.f};
      acc1[m][og] = (f32x4){0.f, 0.f, 0.f, 0.f};
    }

  const size_t xcb = (size_t)b * HW * 2 * CIN;
  const int og0 = octile * OG;

  for (int u = tid; u < NROW * 2 * 8; u += 256) {
    int sub = u & 7, rc = u >> 3;
    int pxi = (rc >> 1) * WP + ((rc & 1) ? (W + 1) : 0);
    *(int4*)&Xs[pxi * 64 + ((sub ^ (pxi & 7)) << 3)] = make_int4(0, 0, 0, 0);
  }

  for (int kc = 0; kc < CIN / 32; ++kc) {
    for (int g0 = tid; g0 < NROW * W * 8; g0 += 256) {
      int sub = g0 & 7, px = g0 >> 3;
      int rr = px / W, col = px % W;
      int gr = r0 - 1 + rr;
      int pxi = rr * WP + col + 1;
      int dst = pxi * 64 + ((sub ^ (pxi & 7)) << 3);
      if (gr >= 0 && gr < H) {
        const short* src = XC + xcb + (size_t)(gr * W + col) * 2 * CIN +
                           ((sub & 4) ? CIN : 0) + kc * 32 + (sub & 3) * 8;
        *(int4*)&Xs[dst] = *(const int4*)src;
      } else {
        *(int4*)&Xs[dst] = make_int4(0, 0, 0, 0);
      }
    }
    {
      const short* src = WF + ((size_t)(kc * 9 + 0) * NOGT + og0) * 1024 + tid * (BSH / 256);
      *(int4*)&Bs[0][tid * (BSH / 256)] = *(const int4*)src;
      if constexpr (OG == 4)
        *(int4*)&Bs[0][tid * 16 + 8] = *(const int4*)(src + 8);
    }
    __syncthreads();
#pragma unroll 1
    for (int t = 0; t < 9; ++t) {
      int4 r0v, r1v;
      if (t < 8) {
        const short* src = WF + ((size_t)(kc * 9 + t + 1) * NOGT + og0) * 1024 + tid * (BSH / 256);
        r0v = *(const int4*)src;
        if constexpr (OG == 4) r1v = *(const int4*)(src + 8);
      }
      const short* bs = Bs[t & 1];
      f16x8 bh[OG], bl[OG];
#pragma unroll
      for (int og = 0; og < OG; ++og) {
        bh[og] = *(const f16x8*)&bs[(og * 2 + 0) * 512 + lane * 8];
        bl[og] = *(const f16x8*)&bs[(og * 2 + 1) * 512 + lane * 8];
      }
      const int tp = (t / 3) * WP + (t % 3);
#pragma unroll
      for (int m = 0; m < 5; ++m) {
        int P = Pbase[m] + tp;
        int base = P * 64, ph = P & 7;
        f16x8 ah = *(const f16x8*)&Xs[base + ((kgrp ^ ph) << 3)];
        f16x8 al = *(const f16x8*)&Xs[base + (((kgrp + 4) ^ ph) << 3)];
#pragma unroll
        for (int og = 0; og < OG; ++og) {
          // operand-swapped: W is A, X is B -> C col=px, row=oc
          acc0[m][og] = __builtin_amdgcn_mfma_f32_16x16x32_f16(bh[og], ah, acc0[m][og], 0, 0, 0);
          acc1[m][og] = __builtin_amdgcn_mfma_f32_16x16x32_f16(bl[og], ah, acc1[m][og], 0, 0, 0);
          acc1[m][og] = __builtin_amdgcn_mfma_f32_16x16x32_f16(bh[og], al, acc1[m][og], 0, 0, 0);
        }
      }
      if (t < 8) {
        *(int4*)&Bs[(t + 1) & 1][tid * (BSH / 256)] = r0v;
        if constexpr (OG == 4)
          *(int4*)&Bs[(t + 1) & 1][tid * 16 + 8] = r1v;
      }
      __syncthreads();
    }
  }
  // ---- epilogue: combine, +bias, leaky, f16-split, NHWC store
#pragma unroll
  for (int og = 0; og < OG; ++og) {
    const int oc0 = octile * OG * 16 + og * 16 + kgrp * 4;
    float4 bv = *(const float4*)&bias2[oc0];
#pragma unroll
    for (int m = 0; m < 5; ++m) {
      int px = tile_px0 + wave * 80 + m * 16 + lm;
      if (px < HW) {
        f32x4 v0 = acc0[m][og], v1 = acc1[m][og];
        float o0 = fmaf(v1[0], 4.8828125e-4f, v0[0]) + bv.x;
        float o1 = fmaf(v1[1], 4.8828125e-4f, v0[1]) + bv.y;
        float o2 = fmaf(v1[2], 4.8828125e-4f, v0[2]) + bv.z;
        float o3 = fmaf(v1[3], 4.8828125e-4f, v0[3]) + bv.w;
        o0 = o0 > 0.f ? o0 : 0.1f * o0;
        o1 = o1 > 0.f ? o1 : 0.1f * o1;
        o2 = o2 > 0.f ? o2 : 0.1f * o2;
        o3 = o3 > 0.f ? o3 : 0.1f * o3;
        short h[4], l[4];
        f16_split(o0, h[0], l[0]); f16_split(o1, h[1], l[1]);
        f16_split(o2, h[2], l[2]); f16_split(o3, h[3], l[3]);
        short* d = ACT + ((size_t)(b * HW + px)) * 2 * COUT + oc0;
        uint2 hv, lv;
        hv.x = pk2(h[0], h[1]); hv.y = pk2(h[2], h[3]);
        lv.x = pk2(l[0], l[1]); lv.y = pk2(l[2], l[3]);
        *(uint2*)d = hv;
        *(uint2*)(d + COUT) = lv;
      }
    }
  }
}

// ======== head 1x1 (255 couts) via f16-split MFMA (4-term) + decode ========
// Block 256 = 4 waves; tile 32 px x 256 oc. Wave w: og block w*4..w*4+4.
// GEMM: zero LDS, zero barriers (direct coalesced global frag loads).
template<int CIN>
__global__ __launch_bounds__(256)
void head_mfma_decode(const short* __restrict__ ACT, const short* __restrict__ WH,
                      const float* __restrict__ pb,
                      int HW, int Wl, float strd, int P0,
                      float aw0, float ah0, float aw1, float ah1, float aw2, float ah2,
                      float* __restrict__ out, float* __restrict__ boxes,
                      float* __restrict__ scb, int* __restrict__ clsb) {
  __shared__ float pred[32 * 256];
  const int tid = threadIdx.x, lane = tid & 63, wave = tid >> 6;
  const int lm = lane & 15, kgrp = lane >> 4;
  const int pt = blockIdx.x, b = blockIdx.y;
  const int p0 = pt * 32;
  const int ogb = wave * 4;
  int pxg[2];
#pragma unroll
  for (int m = 0; m < 2; ++m) pxg[m] = min(p0 + m * 16 + lm, HW - 1);
  const short* actb = ACT + (size_t)b * HW * 2 * CIN;
  f32x4 acc0[2][4], acc1[2][4], acc2[2][4];
#pragma unroll
  for (int m = 0; m < 2; ++m)
#pragma unroll
    for (int og = 0; og < 4; ++og) {
      acc0[m][og] = (f32x4){0.f, 0.f, 0.f, 0.f};
      acc1[m][og] = (f32x4){0.f, 0.f, 0.f, 0.f};
      acc2[m][og] = (f32x4){0.f, 0.f, 0.f, 0.f};
    }
#pragma unroll 2
  for (int kc = 0; kc < CIN / 32; ++kc) {
    f16x8 ah[2], al[2], wh[4], wl[4];
#pragma unroll
    for (int m = 0; m < 2; ++m) {
      const short* s = actb + (size_t)pxg[m] * 2 * CIN + kc * 32 + kgrp * 8;
      ah[m] = *(const f16x8*)s;
      al[m] = *(const f16x8*)(s + CIN);
    }
#pragma unroll
    for (int og = 0; og < 4; ++og) {
      const short* s = WH + ((size_t)(kc * 16 + ogb + og) * 2) * 512 + lane * 8;
      wh[og] = *(const f16x8*)s;
      wl[og] = *(const f16x8*)(s + 512);
    }
#pragma unroll
    for (int m = 0; m < 2; ++m)
#pragma unroll
      for (int og = 0; og < 4; ++og) {
        acc0[m][og] = __builtin_amdgcn_mfma_f32_16x16x32_f16(wh[og], ah[m], acc0[m][og], 0, 0, 0);
        acc1[m][og] = __builtin_amdgcn_mfma_f32_16x16x32_f16(wl[og], ah[m], acc1[m][og], 0, 0, 0);
        acc1[m][og] = __builtin_amdgcn_mfma_f32_16x16x32_f16(wh[og], al[m], acc1[m][og], 0, 0, 0);
        acc2[m][og] = __builtin_amdgcn_mfma_f32_16x16x32_f16(wl[og], al[m], acc2[m][og], 0, 0, 0);
      }
  }
  // ---- +pb, write pred tile (fp32, XOR-swizzled granules)
#pragma unroll
  for (int m = 0; m < 2; ++m) {
    const int pxl = m * 16 + lm;
    const int swz = pxl & 28;
#pragma unroll
    for (int og = 0; og < 4; ++og) {
      const int ch0 = (ogb + og) * 16 + kgrp * 4;
      float4 v;
      const float c = 4.8828125e-4f;
#pragma unroll
      for (int j = 0; j < 4; ++j) {
        float pbv = (ch0 + j < 255) ? pb[ch0 + j] : 0.f;
        float t = fmaf(acc2[m][og][j], c, acc1[m][og][j]);
        (&v.x)[j] = fmaf(t, c, acc0[m][og][j]) + pbv;
      }
      *(float4*)&pred[pxl * 256 + (ch0 ^ swz)] = v;
    }
  }
  __syncthreads();
  // ---- decode: 96 threads = 32 px x 3 anchors
  if (tid < 96) {
    const int px = tid & 31, a = tid >> 5;
    const int p = p0 + px;
    if (p < HW) {
      const int swz = px & 28;
      const float* pr = &pred[px * 256];
#define RD(ch) pr[(ch) ^ swz]
      float conf = RD(a);
      int ch0 = 3 + 80 * a;
      float m = -1e30f; int ci = 0;
      for (int i = 0; i < 80; ++i) {
        float v = RD(ch0 + i);
        if (v > m) { m = v; ci = i; }
      }
      float ssum = 0.f;
      for (int i = 0; i < 80; ++i) ssum += expf(RD(ch0 + i) - m);
      float sig = 1.f / (1.f + expf(-conf));
      float sc = sig / ssum;
      float tx = RD(243 + 4 * a), ty = RD(244 + 4 * a);
      float tw = RD(245 + 4 * a), th = RD(246 + 4 * a);
#undef RD
      float gxx = (float)(p % Wl), gy = (float)(p / Wl);
      float aw = (a == 0) ? aw0 : ((a == 1) ? aw1 : aw2);
      float ah = (a == 0) ? ah0 : ((a == 1) ? ah1 : ah2);
      float cx = (1.f / (1.f + expf(-tx)) + gxx) * strd;
      float cy2 = (1.f / (1.f + expf(-ty)) + gy) * strd;
      float bw = expf(tw) * aw, bh = expf(th) * ah;
      float x1 = fminf(fmaxf((cx - bw * 0.5f) / 640.f, 0.f), 1.f);
      float y1 = fminf(fmaxf((cy2 - bh * 0.5f) / 640.f, 0.f), 1.f);
      float x2 = fminf(fmaxf((cx + bw * 0.5f) / 640.f, 0.f), 1.f);
      float y2 = fminf(fmaxf((cy2 + bh * 0.5f) / 640.f, 0.f), 1.f);
      int n = (P0 + p) * 3 + a;
      size_t gg = (size_t)b * 25200 + n;
      out[gg * 5 + 0] = (x1 + x2) * 0.5f * 640.f;
      out[gg * 5 + 1] = (y1 + y2) * 0.5f * 640.f;
      out[gg * 5 + 2] = (x2 - x1) * 640.f;
      out[gg * 5 + 3] = (y2 - y1) * 640.f;
      out[gg * 5 + 4] = sc;
      out[(size_t)8 * 25200 * 5 + gg] = (float)ci;
      out[(size_t)8 * 25200 * 6 + gg] = 0.f;
      boxes[gg * 4 + 0] = x1; boxes[gg * 4 + 1] = y1;
      boxes[gg * 4 + 2] = x2; boxes[gg * 4 + 3] = y2;
      scb[gg] = sc; clsb[gg] = ci;
    }
  }
}

// ================= top-k (compact + bitonic) =================
__global__ __launch_bounds__(256)
void topk_sort(const float* __restrict__ scb, const float* __restrict__ boxes,
               const int* __restrict__ clsb,
               int* __restrict__ tidx, int* __restrict__ tval, float* __restrict__ tbox) {
  __shared__ ull keys[4096];
  __shared__ int cnt;
  const int b = blockIdx.x, tid = threadIdx.x;
  if (tid == 0) cnt = 0;
  __syncthreads();
  for (int n = tid; n < 25200; n += 256) {
    float s = scb[(size_t)b * 25200 + n];
    if (s >= 0.3f) {
      int p = atomicAdd(&cnt, 1);
      if (p < 4096)
        keys[p] = ((ull)__float_as_uint(s) << 32) | (ull)(0xFFFFFFFFu - (unsigned)n);
    }
  }
  __syncthreads();
  int c = min(cnt, 4096);
  int P2 = 1024;
  while (P2 < c) P2 <<= 1;
  for (int i = c + tid; i < P2; i += 256) keys[i] = 0ull;
  __syncthreads();
  for (int len = 2; len <= P2; len <<= 1) {
    for (int j = len >> 1; j > 0; j >>= 1) {
      for (int x = tid; x < P2; x += 256) {
        int y = x ^ j;
        if (y > x) {
          ull a = keys[x], bb = keys[y];
          bool up = (x & len) == 0;
          if (up ? (a < bb) : (a > bb)) { keys[x] = bb; keys[y] = a; }
        }
      }
      __syncthreads();
    }
  }
  for (int i = tid; i < 1000; i += 256) {
    ull k = keys[i];
    int valid = (k != 0ull) ? 1 : 0;
    int n = valid ? (int)(0xFFFFFFFFu - (unsigned)(k & 0xFFFFFFFFull)) : 0;
    float cls = (float)clsb[(size_t)b * 25200 + n];
    float off = cls * 4.0f;
    const float* bp = &boxes[((size_t)b * 25200 + n) * 4];
    tidx[b * 1000 + i] = n;
    tval[b * 1000 + i] = valid;
    tbox[(b * 1000 + i) * 4 + 0] = bp[0] + off;
    tbox[(b * 1000 + i) * 4 + 1] = bp[1] + off;
    tbox[(b * 1000 + i) * 4 + 2] = bp[2] + off;
    tbox[(b * 1000 + i) * 4 + 3] = bp[3] + off;
  }
}

// ================= pairwise suppression bitmasks =================
__global__ __launch_bounds__(1024)
void supmask(const float* __restrict__ tbox, ull* __restrict__ sup) {
  __shared__ float4 bx[1000];
  __shared__ float ar[1000];
  const int b = blockIdx.x, tid = threadIdx.x;
  for (int i = tid; i < 1000; i += 1024) {
    float4 v = *(const float4*)&tbox[((size_t)b * 1000 + i) * 4];
    bx[i] = v;
    ar[i] = (v.z - v.x) * (v.w - v.y);
  }
  __syncthreads();
  if (tid < 1000) {
    float4 bi = bx[tid];
    float ai = ar[tid];
    ull w = 0;
    for (int j = 0; j < 1000; ++j) {
      float4 bj = bx[j];
      float xx1 = fmaxf(bi.x, bj.x), yy1 = fmaxf(bi.y, bj.y);
      float xx2 = fminf(bi.z, bj.z), yy2 = fminf(bi.w, bj.w);
      float inter = fmaxf(1e-28f, xx2 - xx1) * fmaxf(1e-28f, yy2 - yy1);
      float iou = inter / (ai + ar[j] - inter);
      if (iou > 0.5f) w |= 1ull << (j & 63);
      if ((j & 63) == 63) { sup[((size_t)b * 1000 + tid) * 16 + (j >> 6)] = w; w = 0; }
    }
    sup[((size_t)b * 1000 + tid) * 16 + 15] = w;
  }
}

// ================= greedy NMS (serial, ballot-driven) =================
__global__ __launch_bounds__(64)
void nms_kernel(const ull* __restrict__ sup, const int* __restrict__ tval,
                const int* __restrict__ tidx, float* __restrict__ keep_out) {
  const int b = blockIdx.x, lane = threadIdx.x;
  __shared__ ull slds[64][17];
  ull keepw = 0;
  for (int ch = 0; ch < 16; ++ch) {
    int i0 = ch * 64;
    int nIn = min(64, 1000 - i0);
    for (int k = 0; k < 16; ++k) {
      int linear = k * 64 + lane;
      int row = linear >> 4, w = linear & 15;
      slds[row][w] = (row < nIn) ? sup[((size_t)b * 1000 + i0 + row) * 16 + w] : 0ull;
    }
    int myvalid = (lane < nIn) ? tval[b * 1000 + i0 + lane] : 0;
    int myidx = (lane < nIn) ? tidx[b * 1000 + i0 + lane] : 0;
    __syncthreads();
    for (int li = 0; li < nIn; ++li) {
      ull m = (lane < 16) ? (keepw & slds[li][lane]) : 0ull;
      bool sup_any = __any(m != 0ull);
      int v = __shfl(myvalid, li);
      bool keep_i = v && !sup_any;
      if (keep_i) {
        if (lane == ch) keepw |= 1ull << li;
        if (lane == li) keep_out[(size_t)b * 25200 + myidx] = 1.0f;
      }
    }
    __syncthreads();
  }
}

// ================= launch =================
extern "C" void kernel_launch(void* const* d_in, const int* in_sizes, int n_in,
                              void* d_out, int out_size, void* d_ws, size_t ws_size,
                              hipStream_t stream) {
  const float* p3 = (const float*)d_in[0];
  const float* p4 = (const float*)d_in[1];
  const float* p5 = (const float*)d_in[2];
  auto L = [&](int lvl, int k) { return (const float*)d_in[3 + lvl * 8 + k]; };
  float* out = (float*)d_out;
  char* ws = (char*)d_ws;
  size_t o = 0;
  short* ACT = (short*)(ws + o);   o += (size_t)26214400 * 2;   // NHWC f16 hi/lo
  short* XC  = (short*)(ws + o);   o += (size_t)13107200 * 2;
  short* WF  = (short*)(ws + o);   o += (size_t)9437184 * 2;
  float* bias2 = (float*)(ws + o); o += 2048 * 4;
  float* boxes = (float*)(ws + o); o += (size_t)806400 * 4;
  float* scb = (float*)(ws + o);   o += (size_t)201600 * 4;
  int* clsb = (int*)(ws + o);      o += (size_t)201600 * 4;
  int* tidx = (int*)(ws + o);      o += 8000 * 4;
  int* tval = (int*)(ws + o);      o += 8000 * 4;
  float* tbox = (float*)(ws + o);  o += 32000 * 4;
  ull* sup = (ull*)(ws + o);       o += (size_t)128000 * 8;
  // WH overlays XC tail (hwprep runs after conv consumed XC; xprep of next
  // level runs after head consumed WH -- stream-ordered, no hazard)
  short* WH = XC + (13107200 - 524288);
  float* b2_1 = bias2, *b2_2 = bias2 + 256, *b2_3 = bias2 + 768;

  bfold<<<1, 256, 0, stream>>>(L(0, 1), L(0, 2), L(0, 3), L(0, 4), L(0, 5), b2_1, 256);
  bfold<<<2, 256, 0, stream>>>(L(1, 1), L(1, 2), L(1, 3), L(1, 4), L(1, 5), b2_2, 512);
  bfold<<<4, 256, 0, stream>>>(L(2, 1), L(2, 2), L(2, 3), L(2, 4), L(2, 5), b2_3, 1024);

  // ---- level 1: 128->256, 80x80
  wprep<<<144, 256, 0, stream>>>(L(0, 0), L(0, 2), L(0, 5), WF, 128, 4);
  xprep<<<dim3(50, 4, 8), 256, 0, stream>>>(p3, XC, 6400, 128);
  conv3x3_mfma<128, 256, 80, 80, 4, 4><<<dim3(20, 4, 8), 256, 0, stream>>>(XC, WF, b2_1, ACT);
  hwprep<<<32, 256, 0, stream>>>(L(0, 6), WH, 256);
  head_mfma_decode<256><<<dim3(200, 8), 256, 0, stream>>>(
      ACT, WH, L(0, 7), 6400, 80, 8.f, 0,
      32.64f, 47.68f, 50.24f, 108.16f, 126.72f, 96.32f, out, boxes, scb, clsb);
  // ---- level 2: 256->512, 40x40
  wprep<<<576, 256, 0, stream>>>(L(1, 0), L(1, 2), L(1, 5), WF, 256, 5);
  xprep<<<dim3(13, 8, 8), 256, 0, stream>>>(p4, XC, 1600, 256);
  conv3x3_mfma<256, 512, 40, 40, 8, 4><<<dim3(5, 8, 8), 256, 0, stream>>>(XC, WF, b2_2, ACT);
  hwprep<<<64, 256, 0, stream>>>(L(1, 6), WH, 512);
  head_mfma_decode<512><<<dim3(50, 8), 256, 0, stream>>>(
      ACT, WH, L(1, 7), 1600, 40, 16.f, 6400,
      78.4f, 201.92f, 178.24f, 178.56f, 129.6f, 294.72f, out, boxes, scb, clsb);
  // ---- level 3: 512->1024, 20x20
  wprep<<<2304, 256, 0, stream>>>(L(2, 0), L(2, 2), L(2, 5), WF, 512, 6);
  xprep<<<dim3(4, 16, 8), 256, 0, stream>>>(p5, XC, 400, 512);
  conv3x3_mfma<512, 1024, 20, 20, 16, 2><<<dim3(2, 32, 8), 256, 0, stream>>>(XC, WF, b2_3, ACT);
  hwprep<<<128, 256, 0, stream>>>(L(2, 6), WH, 1024);
  head_mfma_decode<1024><<<dim3(13, 8), 256, 0, stream>>>(
      ACT, WH, L(2, 7), 400, 20, 32.f, 8000,
      331.84f, 194.56f, 227.84f, 325.76f, 365.44f, 358.72f, out, boxes, scb, clsb);
  // ---- NMS pipeline
  topk_sort<<<8, 256, 0, stream>>>(scb, boxes, clsb, tidx, tval, tbox);
  supmask<<<8, 1024, 0, stream>>>(tbox, sup);
  nms_kernel<<<8, 64, 0, stream>>>(sup, tval, tidx, out + (size_t)8 * 25200 * 6);
}

// Round 7
// 999.588 us; speedup vs baseline: 3.6965x; 1.1887x over previous
//
#include <hip/hip_runtime.h>
#include <hip/hip_bf16.h>
#include <stdint.h>
#include <math.h>

typedef unsigned long long ull;
typedef __attribute__((ext_vector_type(8))) _Float16 f16x8;
typedef __attribute__((ext_vector_type(4))) float f32x4;

// f16 split: v ~= hi + lo*2^-11, lo pre-scaled by 2^11 (keeps lo normal-range)
__device__ __forceinline__ void f16_split(float v, short& hi, short& lo) {
  _Float16 h = (_Float16)v;
  float r = v - (float)h;
  _Float16 l = (_Float16)(r * 2048.f);
  hi = __builtin_bit_cast(short, h);
  lo = __builtin_bit_cast(short, l);
}
__device__ __forceinline__ unsigned pk2(short a, short b) {
  return (unsigned)(unsigned short)a | ((unsigned)(unsigned short)b << 16);
}

// ======== prep: x fp32 NCHW -> XC f16 [B][HW][hi:CIN | lo2048:CIN] ========
__global__ __launch_bounds__(256)
void xprep(const float* __restrict__ x, short* __restrict__ XC, int HW, int CIN) {
  __shared__ float T[32 * 132];
  const int p0 = blockIdx.x * 128, c0 = blockIdx.y * 32, b = blockIdx.z;
  const int tid = threadIdx.x;
#pragma unroll
  for (int i = 0; i < 16; ++i) {
    int u = tid + i * 256;
    int ch = u >> 7, px = u & 127;
    int gp = p0 + px;
    float v = 0.f;
    if (gp < HW) v = x[((size_t)b * CIN + c0 + ch) * HW + gp];
    T[ch * 132 + px] = v;
  }
  __syncthreads();
  const int px = tid & 127, half = tid >> 7;
  const int gp = p0 + px;
  if (gp < HW) {
    short h[16], l[16];
#pragma unroll
    for (int k = 0; k < 16; ++k)
      f16_split(T[(half * 16 + k) * 132 + px], h[k], l[k]);
    short* dh = XC + ((size_t)b * HW + gp) * 2 * CIN + c0 + half * 16;
    short* dl = dh + CIN;
    int4 a, bq;
    a.x = pk2(h[0], h[1]); a.y = pk2(h[2], h[3]); a.z = pk2(h[4], h[5]); a.w = pk2(h[6], h[7]);
    bq.x = pk2(h[8], h[9]); bq.y = pk2(h[10], h[11]); bq.z = pk2(h[12], h[13]); bq.w = pk2(h[14], h[15]);
    *(int4*)dh = a; *(int4*)(dh + 8) = bq;
    a.x = pk2(l[0], l[1]); a.y = pk2(l[2], l[3]); a.z = pk2(l[4], l[5]); a.w = pk2(l[6], l[7]);
    bq.x = pk2(l[8], l[9]); bq.y = pk2(l[10], l[11]); bq.z = pk2(l[12], l[13]); bq.w = pk2(l[14], l[15]);
    *(int4*)dl = a; *(int4*)(dl + 8) = bq;
  }
}

// ======== prep: conv weights -> BN-folded f16 hi/lo MFMA fragments ========
// WF layout (shorts): [kc*9+t][og][hl][lane][8j]
__global__ __launch_bounds__(256)
void wprep(const float* __restrict__ w, const float* __restrict__ g,
           const float* __restrict__ v, short* __restrict__ WF, int CIN, int lgNOG) {
  const int NOG = 1 << lgNOG;
  int e = blockIdx.x * 256 + threadIdx.x;
  int lane = e & 63;
  int og = (e >> 6) & (NOG - 1);
  int r = e >> (6 + lgNOG);
  int t = r % 9, kc = r / 9;
  int oc = og * 16 + (lane & 15);
  int icb = kc * 32 + (lane >> 4) * 8;
  float s = g[oc] / sqrtf(v[oc] + 1e-5f);
  short h[8], l[8];
#pragma unroll
  for (int j = 0; j < 8; ++j) {
    float val = w[((size_t)oc * CIN + icb + j) * 9 + t] * s;
    f16_split(val, h[j], l[j]);
  }
  size_t base = ((size_t)(kc * 9 + t) * NOG + og) * 1024 + lane * 8;
  int4 a;
  a.x = pk2(h[0], h[1]); a.y = pk2(h[2], h[3]); a.z = pk2(h[4], h[5]); a.w = pk2(h[6], h[7]);
  *(int4*)&WF[base] = a;
  a.x = pk2(l[0], l[1]); a.y = pk2(l[2], l[3]); a.z = pk2(l[4], l[5]); a.w = pk2(l[6], l[7]);
  *(int4*)&WF[base + 512] = a;
}

// ======== prep: head 1x1 weights -> f16 hi/lo fragments ========
// WH layout (shorts): [kc][og(16)][hl][lane][8j] ; oc>=255 zero-padded
__global__ __launch_bounds__(256)
void hwprep(const float* __restrict__ pw, short* __restrict__ WH, int CIN) {
  int e = blockIdx.x * 256 + threadIdx.x;   // (kc, og, lane)
  int lane = e & 63;
  int og = (e >> 6) & 15;
  int kc = e >> 10;
  int oc = og * 16 + (lane & 15);
  int ic0 = kc * 32 + (lane >> 4) * 8;
  short h[8], l[8];
#pragma unroll
  for (int j = 0; j < 8; ++j) {
    float val = (oc < 255) ? pw[(size_t)oc * CIN + ic0 + j] : 0.f;
    f16_split(val, h[j], l[j]);
  }
  size_t base = ((size_t)(kc * 16 + og) * 2) * 512 + lane * 8;
  int4 a;
  a.x = pk2(h[0], h[1]); a.y = pk2(h[2], h[3]); a.z = pk2(h[4], h[5]); a.w = pk2(h[6], h[7]);
  *(int4*)&WH[base] = a;
  a.x = pk2(l[0], l[1]); a.y = pk2(l[2], l[3]); a.z = pk2(l[4], l[5]); a.w = pk2(l[6], l[7]);
  *(int4*)&WH[base + 512] = a;
}

__global__ __launch_bounds__(256)
void bfold(const float* __restrict__ b, const float* __restrict__ g,
           const float* __restrict__ be, const float* __restrict__ m,
           const float* __restrict__ v, float* __restrict__ bias2, int n) {
  int i = blockIdx.x * 256 + threadIdx.x;
  if (i < n) bias2[i] = (b[i] - m[i]) * (g[i] / sqrtf(v[i] + 1e-5f)) + be[i];
}

// ======== Conv3x3 SAME + folded-BN + LeakyReLU via f16-split MFMA ========
// Operand-swapped (W as A-operand): C col=px, row=oc -> epilogue writes
// ACT directly in NHWC f16 hi/lo format [B][HW][hi:COUT | lo2048:COUT].
template<int CIN, int COUT, int H, int W, int ROWS, int OG>
__global__ __launch_bounds__(256, 2)
void conv3x3_mfma(const short* __restrict__ XC, const short* __restrict__ WF,
                  const float* __restrict__ bias2, short* __restrict__ ACT) {
  constexpr int HW = H * W, WP = W + 2, NROW = ROWS + 2, NOGT = COUT / 16;
  constexpr int BSH = OG * 1024;
  __shared__ short Xs[NROW * WP * 64];
  __shared__ short Bs[2][BSH];
  const int tid = threadIdx.x, lane = tid & 63, wave = tid >> 6;
  const int tile = blockIdx.x, octile = blockIdx.y, b = blockIdx.z;
  const int r0 = tile * ROWS;
  const int tile_px0 = r0 * W;
  const int kgrp = lane >> 4, lm = lane & 15;
  int Pbase[5];
#pragma unroll
  for (int m = 0; m < 5; ++m) {
    int pl = wave * 80 + m * 16 + lm;
    Pbase[m] = (pl / W) * WP + (pl % W);
  }
  f32x4 acc0[5][OG], acc1[5][OG];
#pragma unroll
  for (int m = 0; m < 5; ++m)
#pragma unroll
    for (int og = 0; og < OG; ++og) {
      acc0[m][og] = (f32x4){0.f, 0.f, 0.f, 0.f};
      acc1[m][og] = (f32x4){0.f, 0.f, 0.f, 0.f};
    }

  const size_t xcb = (size_t)b * HW * 2 * CIN;
  const int og0 = octile * OG;

  for (int u = tid; u < NROW * 2 * 8; u += 256) {
    int sub = u & 7, rc = u >> 3;
    int pxi = (rc >> 1) * WP + ((rc & 1) ? (W + 1) : 0);
    *(int4*)&Xs[pxi * 64 + ((sub ^ (pxi & 7)) << 3)] = make_int4(0, 0, 0, 0);
  }

  for (int kc = 0; kc < CIN / 32; ++kc) {
    for (int g0 = tid; g0 < NROW * W * 8; g0 += 256) {
      int sub = g0 & 7, px = g0 >> 3;
      int rr = px / W, col = px % W;
      int gr = r0 - 1 + rr;
      int pxi = rr * WP + col + 1;
      int dst = pxi * 64 + ((sub ^ (pxi & 7)) << 3);
      if (gr >= 0 && gr < H) {
        const short* src = XC + xcb + (size_t)(gr * W + col) * 2 * CIN +
                           ((sub & 4) ? CIN : 0) + kc * 32 + (sub & 3) * 8;
        *(int4*)&Xs[dst] = *(const int4*)src;
      } else {
        *(int4*)&Xs[dst] = make_int4(0, 0, 0, 0);
      }
    }
    {
      const short* src = WF + ((size_t)(kc * 9 + 0) * NOGT + og0) * 1024 + tid * (BSH / 256);
      *(int4*)&Bs[0][tid * (BSH / 256)] = *(const int4*)src;
      if constexpr (OG == 4)
        *(int4*)&Bs[0][tid * 16 + 8] = *(const int4*)(src + 8);
    }
    __syncthreads();
#pragma unroll 1
    for (int t = 0; t < 9; ++t) {
      int4 r0v, r1v;
      if (t < 8) {
        const short* src = WF + ((size_t)(kc * 9 + t + 1) * NOGT + og0) * 1024 + tid * (BSH / 256);
        r0v = *(const int4*)src;
        if constexpr (OG == 4) r1v = *(const int4*)(src + 8);
      }
      const short* bs = Bs[t & 1];
      f16x8 bh[OG], bl[OG];
#pragma unroll
      for (int og = 0; og < OG; ++og) {
        bh[og] = *(const f16x8*)&bs[(og * 2 + 0) * 512 + lane * 8];
        bl[og] = *(const f16x8*)&bs[(og * 2 + 1) * 512 + lane * 8];
      }
      const int tp = (t / 3) * WP + (t % 3);
#pragma unroll
      for (int m = 0; m < 5; ++m) {
        int P = Pbase[m] + tp;
        int base = P * 64, ph = P & 7;
        f16x8 ah = *(const f16x8*)&Xs[base + ((kgrp ^ ph) << 3)];
        f16x8 al = *(const f16x8*)&Xs[base + (((kgrp + 4) ^ ph) << 3)];
#pragma unroll
        for (int og = 0; og < OG; ++og) {
          // operand-swapped: W is A, X is B -> C col=px, row=oc
          acc0[m][og] = __builtin_amdgcn_mfma_f32_16x16x32_f16(bh[og], ah, acc0[m][og], 0, 0, 0);
          acc1[m][og] = __builtin_amdgcn_mfma_f32_16x16x32_f16(bl[og], ah, acc1[m][og], 0, 0, 0);
          acc1[m][og] = __builtin_amdgcn_mfma_f32_16x16x32_f16(bh[og], al, acc1[m][og], 0, 0, 0);
        }
      }
      if (t < 8) {
        *(int4*)&Bs[(t + 1) & 1][tid * (BSH / 256)] = r0v;
        if constexpr (OG == 4)
          *(int4*)&Bs[(t + 1) & 1][tid * 16 + 8] = r1v;
      }
      __syncthreads();
    }
  }
  // ---- epilogue: combine, +bias, leaky, f16-split, NHWC store
#pragma unroll
  for (int og = 0; og < OG; ++og) {
    const int oc0 = octile * OG * 16 + og * 16 + kgrp * 4;
    float4 bv = *(const float4*)&bias2[oc0];
#pragma unroll
    for (int m = 0; m < 5; ++m) {
      int px = tile_px0 + wave * 80 + m * 16 + lm;
      if (px < HW) {
        f32x4 v0 = acc0[m][og], v1 = acc1[m][og];
        float o0 = fmaf(v1[0], 4.8828125e-4f, v0[0]) + bv.x;
        float o1 = fmaf(v1[1], 4.8828125e-4f, v0[1]) + bv.y;
        float o2 = fmaf(v1[2], 4.8828125e-4f, v0[2]) + bv.z;
        float o3 = fmaf(v1[3], 4.8828125e-4f, v0[3]) + bv.w;
        o0 = o0 > 0.f ? o0 : 0.1f * o0;
        o1 = o1 > 0.f ? o1 : 0.1f * o1;
        o2 = o2 > 0.f ? o2 : 0.1f * o2;
        o3 = o3 > 0.f ? o3 : 0.1f * o3;
        short h[4], l[4];
        f16_split(o0, h[0], l[0]); f16_split(o1, h[1], l[1]);
        f16_split(o2, h[2], l[2]); f16_split(o3, h[3], l[3]);
        short* d = ACT + ((size_t)(b * HW + px)) * 2 * COUT + oc0;
        uint2 hv, lv;
        hv.x = pk2(h[0], h[1]); hv.y = pk2(h[2], h[3]);
        lv.x = pk2(l[0], l[1]); lv.y = pk2(l[2], l[3]);
        *(uint2*)d = hv;
        *(uint2*)(d + COUT) = lv;
      }
    }
  }
}

// ======== head 1x1 (255 couts) via f16-split MFMA (4-term) + decode ========
// Block 256 = 4 waves; tile 32 px x 256 oc. Wave w: og block w*4..w*4+4.
// GEMM: zero LDS, zero barriers (direct coalesced global frag loads).
template<int CIN>
__global__ __launch_bounds__(256)
void head_mfma_decode(const short* __restrict__ ACT, const short* __restrict__ WH,
                      const float* __restrict__ pb,
                      int HW, int Wl, float strd, int P0,
                      float aw0, float ah0, float aw1, float ah1, float aw2, float ah2,
                      float* __restrict__ out, float* __restrict__ boxes,
                      float* __restrict__ scb, int* __restrict__ clsb) {
  __shared__ float pred[32 * 256];
  const int tid = threadIdx.x, lane = tid & 63, wave = tid >> 6;
  const int lm = lane & 15, kgrp = lane >> 4;
  const int pt = blockIdx.x, b = blockIdx.y;
  const int p0 = pt * 32;
  const int ogb = wave * 4;
  int pxg[2];
#pragma unroll
  for (int m = 0; m < 2; ++m) pxg[m] = min(p0 + m * 16 + lm, HW - 1);
  const short* actb = ACT + (size_t)b * HW * 2 * CIN;
  f32x4 acc0[2][4], acc1[2][4], acc2[2][4];
#pragma unroll
  for (int m = 0; m < 2; ++m)
#pragma unroll
    for (int og = 0; og < 4; ++og) {
      acc0[m][og] = (f32x4){0.f, 0.f, 0.f, 0.f};
      acc1[m][og] = (f32x4){0.f, 0.f, 0.f, 0.f};
      acc2[m][og] = (f32x4){0.f, 0.f, 0.f, 0.f};
    }
#pragma unroll 2
  for (int kc = 0; kc < CIN / 32; ++kc) {
    f16x8 ah[2], al[2], wh[4], wl[4];
#pragma unroll
    for (int m = 0; m < 2; ++m) {
      const short* s = actb + (size_t)pxg[m] * 2 * CIN + kc * 32 + kgrp * 8;
      ah[m] = *(const f16x8*)s;
      al[m] = *(const f16x8*)(s + CIN);
    }
#pragma unroll
    for (int og = 0; og < 4; ++og) {
      const short* s = WH + ((size_t)(kc * 16 + ogb + og) * 2) * 512 + lane * 8;
      wh[og] = *(const f16x8*)s;
      wl[og] = *(const f16x8*)(s + 512);
    }
#pragma unroll
    for (int m = 0; m < 2; ++m)
#pragma unroll
      for (int og = 0; og < 4; ++og) {
        acc0[m][og] = __builtin_amdgcn_mfma_f32_16x16x32_f16(wh[og], ah[m], acc0[m][og], 0, 0, 0);
        acc1[m][og] = __builtin_amdgcn_mfma_f32_16x16x32_f16(wl[og], ah[m], acc1[m][og], 0, 0, 0);
        acc1[m][og] = __builtin_amdgcn_mfma_f32_16x16x32_f16(wh[og], al[m], acc1[m][og], 0, 0, 0);
        acc2[m][og] = __builtin_amdgcn_mfma_f32_16x16x32_f16(wl[og], al[m], acc2[m][og], 0, 0, 0);
      }
  }
  // ---- +pb, write pred tile (fp32, XOR-swizzled granules)
#pragma unroll
  for (int m = 0; m < 2; ++m) {
    const int pxl = m * 16 + lm;
    const int swz = pxl & 28;
#pragma unroll
    for (int og = 0; og < 4; ++og) {
      const int ch0 = (ogb + og) * 16 + kgrp * 4;
      float4 v;
      const float c = 4.8828125e-4f;
#pragma unroll
      for (int j = 0; j < 4; ++j) {
        float pbv = (ch0 + j < 255) ? pb[ch0 + j] : 0.f;
        float t = fmaf(acc2[m][og][j], c, acc1[m][og][j]);
        (&v.x)[j] = fmaf(t, c, acc0[m][og][j]) + pbv;
      }
      *(float4*)&pred[pxl * 256 + (ch0 ^ swz)] = v;
    }
  }
  __syncthreads();
  // ---- decode: 96 threads = 32 px x 3 anchors
  if (tid < 96) {
    const int px = tid & 31, a = tid >> 5;
    const int p = p0 + px;
    if (p < HW) {
      const int swz = px & 28;
      const float* pr = &pred[px * 256];
#define RD(ch) pr[(ch) ^ swz]
      float conf = RD(a);
      int ch0 = 3 + 80 * a;
      float m = -1e30f; int ci = 0;
      for (int i = 0; i < 80; ++i) {
        float v = RD(ch0 + i);
        if (v > m) { m = v; ci = i; }
      }
      float ssum = 0.f;
      for (int i = 0; i < 80; ++i) ssum += expf(RD(ch0 + i) - m);
      float sig = 1.f / (1.f + expf(-conf));
      float sc = sig / ssum;
      float tx = RD(243 + 4 * a), ty = RD(244 + 4 * a);
      float tw = RD(245 + 4 * a), th = RD(246 + 4 * a);
#undef RD
      float gxx = (float)(p % Wl), gy = (float)(p / Wl);
      float aw = (a == 0) ? aw0 : ((a == 1) ? aw1 : aw2);
      float ah = (a == 0) ? ah0 : ((a == 1) ? ah1 : ah2);
      float cx = (1.f / (1.f + expf(-tx)) + gxx) * strd;
      float cy2 = (1.f / (1.f + expf(-ty)) + gy) * strd;
      float bw = expf(tw) * aw, bh = expf(th) * ah;
      float x1 = fminf(fmaxf((cx - bw * 0.5f) / 640.f, 0.f), 1.f);
      float y1 = fminf(fmaxf((cy2 - bh * 0.5f) / 640.f, 0.f), 1.f);
      float x2 = fminf(fmaxf((cx + bw * 0.5f) / 640.f, 0.f), 1.f);
      float y2 = fminf(fmaxf((cy2 + bh * 0.5f) / 640.f, 0.f), 1.f);
      int n = (P0 + p) * 3 + a;
      size_t gg = (size_t)b * 25200 + n;
      out[gg * 5 + 0] = (x1 + x2) * 0.5f * 640.f;
      out[gg * 5 + 1] = (y1 + y2) * 0.5f * 640.f;
      out[gg * 5 + 2] = (x2 - x1) * 640.f;
      out[gg * 5 + 3] = (y2 - y1) * 640.f;
      out[gg * 5 + 4] = sc;
      out[(size_t)8 * 25200 * 5 + gg] = (float)ci;
      out[(size_t)8 * 25200 * 6 + gg] = 0.f;
      boxes[gg * 4 + 0] = x1; boxes[gg * 4 + 1] = y1;
      boxes[gg * 4 + 2] = x2; boxes[gg * 4 + 3] = y2;
      scb[gg] = sc; clsb[gg] = ci;
    }
  }
}

// ================= top-k (compact + bitonic) =================
__global__ __launch_bounds__(256)
void topk_sort(const float* __restrict__ scb, const float* __restrict__ boxes,
               const int* __restrict__ clsb,
               int* __restrict__ tidx, int* __restrict__ tval, float* __restrict__ tbox) {
  __shared__ ull keys[4096];
  __shared__ int cnt;
  const int b = blockIdx.x, tid = threadIdx.x;
  if (tid == 0) cnt = 0;
  __syncthreads();
  for (int n = tid; n < 25200; n += 256) {
    float s = scb[(size_t)b * 25200 + n];
    if (s >= 0.3f) {
      int p = atomicAdd(&cnt, 1);
      if (p < 4096)
        keys[p] = ((ull)__float_as_uint(s) << 32) | (ull)(0xFFFFFFFFu - (unsigned)n);
    }
  }
  __syncthreads();
  int c = min(cnt, 4096);
  int P2 = 1024;
  while (P2 < c) P2 <<= 1;
  for (int i = c + tid; i < P2; i += 256) keys[i] = 0ull;
  __syncthreads();
  for (int len = 2; len <= P2; len <<= 1) {
    for (int j = len >> 1; j > 0; j >>= 1) {
      for (int x = tid; x < P2; x += 256) {
        int y = x ^ j;
        if (y > x) {
          ull a = keys[x], bb = keys[y];
          bool up = (x & len) == 0;
          if (up ? (a < bb) : (a > bb)) { keys[x] = bb; keys[y] = a; }
        }
      }
      __syncthreads();
    }
  }
  for (int i = tid; i < 1000; i += 256) {
    ull k = keys[i];
    int valid = (k != 0ull) ? 1 : 0;
    int n = valid ? (int)(0xFFFFFFFFu - (unsigned)(k & 0xFFFFFFFFull)) : 0;
    float cls = (float)clsb[(size_t)b * 25200 + n];
    float off = cls * 4.0f;
    const float* bp = &boxes[((size_t)b * 25200 + n) * 4];
    tidx[b * 1000 + i] = n;
    tval[b * 1000 + i] = valid;
    tbox[(b * 1000 + i) * 4 + 0] = bp[0] + off;
    tbox[(b * 1000 + i) * 4 + 1] = bp[1] + off;
    tbox[(b * 1000 + i) * 4 + 2] = bp[2] + off;
    tbox[(b * 1000 + i) * 4 + 3] = bp[3] + off;
  }
}

// ====== pairwise suppression bitmasks: grid (16 j-chunks, 8 batches) ======
// Each block: 64 j-boxes staged in LDS; thread i computes one 64-bit word.
__global__ __launch_bounds__(1024)
void supmask(const float* __restrict__ tbox, ull* __restrict__ sup) {
  __shared__ float4 bj[64];
  __shared__ float arj[64];
  const int jc = blockIdx.x, b = blockIdx.y;
  const int tid = threadIdx.x;
  if (tid < 64) {
    int j = min(jc * 64 + tid, 999);   // clamp: spurious bits land in word-15
    float4 v = *(const float4*)&tbox[((size_t)b * 1000 + j) * 4];
    bj[tid] = v;                       // positions >=40, never set in keepw
    arj[tid] = (v.z - v.x) * (v.w - v.y);
  }
  __syncthreads();
  if (tid < 1000) {
    float4 bi = *(const float4*)&tbox[((size_t)b * 1000 + tid) * 4];
    float ai = (bi.z - bi.x) * (bi.w - bi.y);
    ull w = 0;
#pragma unroll 8
    for (int j = 0; j < 64; ++j) {
      float4 bv = bj[j];
      float xx1 = fmaxf(bi.x, bv.x), yy1 = fmaxf(bi.y, bv.y);
      float xx2 = fminf(bi.z, bv.z), yy2 = fminf(bi.w, bv.w);
      float inter = fmaxf(1e-28f, xx2 - xx1) * fmaxf(1e-28f, yy2 - yy1);
      float iou = inter / (ai + arj[j] - inter);
      if (iou > 0.5f) w |= 1ull << j;
    }
    sup[((size_t)b * 1000 + tid) * 16 + jc] = w;
  }
}

// ================= greedy NMS (serial, ballot-driven) =================
__global__ __launch_bounds__(64)
void nms_kernel(const ull* __restrict__ sup, const int* __restrict__ tval,
                const int* __restrict__ tidx, float* __restrict__ keep_out) {
  const int b = blockIdx.x, lane = threadIdx.x;
  __shared__ ull slds[64][17];
  ull keepw = 0;
  for (int ch = 0; ch < 16; ++ch) {
    int i0 = ch * 64;
    int nIn = min(64, 1000 - i0);
    for (int k = 0; k < 16; ++k) {
      int linear = k * 64 + lane;
      int row = linear >> 4, w = linear & 15;
      slds[row][w] = (row < nIn) ? sup[((size_t)b * 1000 + i0 + row) * 16 + w] : 0ull;
    }
    int myvalid = (lane < nIn) ? tval[b * 1000 + i0 + lane] : 0;
    int myidx = (lane < nIn) ? tidx[b * 1000 + i0 + lane] : 0;
    __syncthreads();
    for (int li = 0; li < nIn; ++li) {
      ull m = (lane < 16) ? (keepw & slds[li][lane]) : 0ull;
      bool sup_any = __any(m != 0ull);
      int v = __shfl(myvalid, li);
      bool keep_i = v && !sup_any;
      if (keep_i) {
        if (lane == ch) keepw |= 1ull << li;
        if (lane == li) keep_out[(size_t)b * 25200 + myidx] = 1.0f;
      }
    }
    __syncthreads();
  }
}

// ================= launch =================
extern "C" void kernel_launch(void* const* d_in, const int* in_sizes, int n_in,
                              void* d_out, int out_size, void* d_ws, size_t ws_size,
                              hipStream_t stream) {
  const float* p3 = (const float*)d_in[0];
  const float* p4 = (const float*)d_in[1];
  const float* p5 = (const float*)d_in[2];
  auto L = [&](int lvl, int k) { return (const float*)d_in[3 + lvl * 8 + k]; };
  float* out = (float*)d_out;
  char* ws = (char*)d_ws;
  size_t o = 0;
  short* ACT = (short*)(ws + o);   o += (size_t)26214400 * 2;   // NHWC f16 hi/lo
  short* XC  = (short*)(ws + o);   o += (size_t)13107200 * 2;
  short* WF  = (short*)(ws + o);   o += (size_t)9437184 * 2;
  float* bias2 = (float*)(ws + o); o += 2048 * 4;
  float* boxes = (float*)(ws + o); o += (size_t)806400 * 4;
  float* scb = (float*)(ws + o);   o += (size_t)201600 * 4;
  int* clsb = (int*)(ws + o);      o += (size_t)201600 * 4;
  int* tidx = (int*)(ws + o);      o += 8000 * 4;
  int* tval = (int*)(ws + o);      o += 8000 * 4;
  float* tbox = (float*)(ws + o);  o += 32000 * 4;
  ull* sup = (ull*)(ws + o);       o += (size_t)128000 * 8;
  // WH overlays XC tail (hwprep runs after conv consumed XC; xprep of next
  // level runs after head consumed WH -- stream-ordered, no hazard)
  short* WH = XC + (13107200 - 524288);
  float* b2_1 = bias2, *b2_2 = bias2 + 256, *b2_3 = bias2 + 768;

  bfold<<<1, 256, 0, stream>>>(L(0, 1), L(0, 2), L(0, 3), L(0, 4), L(0, 5), b2_1, 256);
  bfold<<<2, 256, 0, stream>>>(L(1, 1), L(1, 2), L(1, 3), L(1, 4), L(1, 5), b2_2, 512);
  bfold<<<4, 256, 0, stream>>>(L(2, 1), L(2, 2), L(2, 3), L(2, 4), L(2, 5), b2_3, 1024);

  // ---- level 1: 128->256, 80x80
  wprep<<<144, 256, 0, stream>>>(L(0, 0), L(0, 2), L(0, 5), WF, 128, 4);
  xprep<<<dim3(50, 4, 8), 256, 0, stream>>>(p3, XC, 6400, 128);
  conv3x3_mfma<128, 256, 80, 80, 4, 4><<<dim3(20, 4, 8), 256, 0, stream>>>(XC, WF, b2_1, ACT);
  hwprep<<<32, 256, 0, stream>>>(L(0, 6), WH, 256);
  head_mfma_decode<256><<<dim3(200, 8), 256, 0, stream>>>(
      ACT, WH, L(0, 7), 6400, 80, 8.f, 0,
      32.64f, 47.68f, 50.24f, 108.16f, 126.72f, 96.32f, out, boxes, scb, clsb);
  // ---- level 2: 256->512, 40x40
  wprep<<<576, 256, 0, stream>>>(L(1, 0), L(1, 2), L(1, 5), WF, 256, 5);
  xprep<<<dim3(13, 8, 8), 256, 0, stream>>>(p4, XC, 1600, 256);
  conv3x3_mfma<256, 512, 40, 40, 8, 4><<<dim3(5, 8, 8), 256, 0, stream>>>(XC, WF, b2_2, ACT);
  hwprep<<<64, 256, 0, stream>>>(L(1, 6), WH, 512);
  head_mfma_decode<512><<<dim3(50, 8), 256, 0, stream>>>(
      ACT, WH, L(1, 7), 1600, 40, 16.f, 6400,
      78.4f, 201.92f, 178.24f, 178.56f, 129.6f, 294.72f, out, boxes, scb, clsb);
  // ---- level 3: 512->1024, 20x20
  wprep<<<2304, 256, 0, stream>>>(L(2, 0), L(2, 2), L(2, 5), WF, 512, 6);
  xprep<<<dim3(4, 16, 8), 256, 0, stream>>>(p5, XC, 400, 512);
  conv3x3_mfma<512, 1024, 20, 20, 16, 2><<<dim3(2, 32, 8), 256, 0, stream>>>(XC, WF, b2_3, ACT);
  hwprep<<<128, 256, 0, stream>>>(L(2, 6), WH, 1024);
  head_mfma_decode<1024><<<dim3(13, 8), 256, 0, stream>>>(
      ACT, WH, L(2, 7), 400, 20, 32.f, 8000,
      331.84f, 194.56f, 227.84f, 325.76f, 365.44f, 358.72f, out, boxes, scb, clsb);
  // ---- NMS pipeline
  topk_sort<<<8, 256, 0, stream>>>(scb, boxes, clsb, tidx, tval, tbox);
  supmask<<<dim3(16, 8), 1024, 0, stream>>>(tbox, sup);
  nms_kernel<<<8, 64, 0, stream>>>(sup, tval, tidx, out + (size_t)8 * 25200 * 6);
}

// Round 8
// 861.254 us; speedup vs baseline: 4.2903x; 1.1606x over previous
//
#include <hip/hip_runtime.h>
#include <hip/hip_bf16.h>
#include <stdint.h>
#include <math.h>

typedef unsigned long long ull;
typedef __attribute__((ext_vector_type(8))) _Float16 f16x8;
typedef __attribute__((ext_vector_type(4))) float f32x4;

// f16 split: v ~= hi + lo*2^-11, lo pre-scaled by 2^11 (keeps lo normal-range)
__device__ __forceinline__ void f16_split(float v, short& hi, short& lo) {
  _Float16 h = (_Float16)v;
  float r = v - (float)h;
  _Float16 l = (_Float16)(r * 2048.f);
  hi = __builtin_bit_cast(short, h);
  lo = __builtin_bit_cast(short, l);
}
__device__ __forceinline__ unsigned pk2(short a, short b) {
  return (unsigned)(unsigned short)a | ((unsigned)(unsigned short)b << 16);
}

// ======== prep: x fp32 NCHW -> XC f16 [B][HW][hi:CIN | lo2048:CIN] ========
__global__ __launch_bounds__(256)
void xprep(const float* __restrict__ x, short* __restrict__ XC, int HW, int CIN) {
  __shared__ float T[32 * 132];
  const int p0 = blockIdx.x * 128, c0 = blockIdx.y * 32, b = blockIdx.z;
  const int tid = threadIdx.x;
#pragma unroll
  for (int i = 0; i < 16; ++i) {
    int u = tid + i * 256;
    int ch = u >> 7, px = u & 127;
    int gp = p0 + px;
    float v = 0.f;
    if (gp < HW) v = x[((size_t)b * CIN + c0 + ch) * HW + gp];
    T[ch * 132 + px] = v;
  }
  __syncthreads();
  const int px = tid & 127, half = tid >> 7;
  const int gp = p0 + px;
  if (gp < HW) {
    short h[16], l[16];
#pragma unroll
    for (int k = 0; k < 16; ++k)
      f16_split(T[(half * 16 + k) * 132 + px], h[k], l[k]);
    short* dh = XC + ((size_t)b * HW + gp) * 2 * CIN + c0 + half * 16;
    short* dl = dh + CIN;
    int4 a, bq;
    a.x = pk2(h[0], h[1]); a.y = pk2(h[2], h[3]); a.z = pk2(h[4], h[5]); a.w = pk2(h[6], h[7]);
    bq.x = pk2(h[8], h[9]); bq.y = pk2(h[10], h[11]); bq.z = pk2(h[12], h[13]); bq.w = pk2(h[14], h[15]);
    *(int4*)dh = a; *(int4*)(dh + 8) = bq;
    a.x = pk2(l[0], l[1]); a.y = pk2(l[2], l[3]); a.z = pk2(l[4], l[5]); a.w = pk2(l[6], l[7]);
    bq.x = pk2(l[8], l[9]); bq.y = pk2(l[10], l[11]); bq.z = pk2(l[12], l[13]); bq.w = pk2(l[14], l[15]);
    *(int4*)dl = a; *(int4*)(dl + 8) = bq;
  }
}

// ======== prep: conv weights -> BN-folded f16 hi/lo MFMA fragments ========
// WF layout (shorts): [kc*9+t][og][hl][lane][8j]
__global__ __launch_bounds__(256)
void wprep(const float* __restrict__ w, const float* __restrict__ g,
           const float* __restrict__ v, short* __restrict__ WF, int CIN, int lgNOG) {
  const int NOG = 1 << lgNOG;
  int e = blockIdx.x * 256 + threadIdx.x;
  int lane = e & 63;
  int og = (e >> 6) & (NOG - 1);
  int r = e >> (6 + lgNOG);
  int t = r % 9, kc = r / 9;
  int oc = og * 16 + (lane & 15);
  int icb = kc * 32 + (lane >> 4) * 8;
  float s = g[oc] / sqrtf(v[oc] + 1e-5f);
  short h[8], l[8];
#pragma unroll
  for (int j = 0; j < 8; ++j) {
    float val = w[((size_t)oc * CIN + icb + j) * 9 + t] * s;
    f16_split(val, h[j], l[j]);
  }
  size_t base = ((size_t)(kc * 9 + t) * NOG + og) * 1024 + lane * 8;
  int4 a;
  a.x = pk2(h[0], h[1]); a.y = pk2(h[2], h[3]); a.z = pk2(h[4], h[5]); a.w = pk2(h[6], h[7]);
  *(int4*)&WF[base] = a;
  a.x = pk2(l[0], l[1]); a.y = pk2(l[2], l[3]); a.z = pk2(l[4], l[5]); a.w = pk2(l[6], l[7]);
  *(int4*)&WF[base + 512] = a;
}

// ======== prep: head 1x1 weights -> f16 hi/lo fragments ========
// WH layout (shorts): [kc][og(16)][hl][lane][8j] ; oc>=255 zero-padded
__global__ __launch_bounds__(256)
void hwprep(const float* __restrict__ pw, short* __restrict__ WH, int CIN) {
  int e = blockIdx.x * 256 + threadIdx.x;   // (kc, og, lane)
  int lane = e & 63;
  int og = (e >> 6) & 15;
  int kc = e >> 10;
  int oc = og * 16 + (lane & 15);
  int ic0 = kc * 32 + (lane >> 4) * 8;
  short h[8], l[8];
#pragma unroll
  for (int j = 0; j < 8; ++j) {
    float val = (oc < 255) ? pw[(size_t)oc * CIN + ic0 + j] : 0.f;
    f16_split(val, h[j], l[j]);
  }
  size_t base = ((size_t)(kc * 16 + og) * 2) * 512 + lane * 8;
  int4 a;
  a.x = pk2(h[0], h[1]); a.y = pk2(h[2], h[3]); a.z = pk2(h[4], h[5]); a.w = pk2(h[6], h[7]);
  *(int4*)&WH[base] = a;
  a.x = pk2(l[0], l[1]); a.y = pk2(l[2], l[3]); a.z = pk2(l[4], l[5]); a.w = pk2(l[6], l[7]);
  *(int4*)&WH[base + 512] = a;
}

__global__ __launch_bounds__(256)
void bfold(const float* __restrict__ b, const float* __restrict__ g,
           const float* __restrict__ be, const float* __restrict__ m,
           const float* __restrict__ v, float* __restrict__ bias2, int n) {
  int i = blockIdx.x * 256 + threadIdx.x;
  if (i < n) bias2[i] = (b[i] - m[i]) * (g[i] / sqrtf(v[i] + 1e-5f)) + be[i];
}

// ======== Conv3x3 SAME + folded-BN + LeakyReLU via f16-split MFMA ========
// Operand-swapped (W as A-operand): C col=px, row=oc -> epilogue writes
// ACT directly in NHWC f16 hi/lo format [B][HW][hi:COUT | lo2048:COUT].
template<int CIN, int COUT, int H, int W, int ROWS, int OG>
__global__ __launch_bounds__(256, 2)
void conv3x3_mfma(const short* __restrict__ XC, const short* __restrict__ WF,
                  const float* __restrict__ bias2, short* __restrict__ ACT) {
  constexpr int HW = H * W, WP = W + 2, NROW = ROWS + 2, NOGT = COUT / 16;
  constexpr int BSH = OG * 1024;
  __shared__ short Xs[NROW * WP * 64];
  __shared__ short Bs[2][BSH];
  const int tid = threadIdx.x, lane = tid & 63, wave = tid >> 6;
  const int tile = blockIdx.x, octile = blockIdx.y, b = blockIdx.z;
  const int r0 = tile * ROWS;
  const int tile_px0 = r0 * W;
  const int kgrp = lane >> 4, lm = lane & 15;
  int Pbase[5];
#pragma unroll
  for (int m = 0; m < 5; ++m) {
    int pl = wave * 80 + m * 16 + lm;
    Pbase[m] = (pl / W) * WP + (pl % W);
  }
  f32x4 acc0[5][OG], acc1[5][OG];
#pragma unroll
  for (int m = 0; m < 5; ++m)
#pragma unroll
    for (int og = 0; og < OG; ++og) {
      acc0[m][og] = (f32x4){0.f, 0.f, 0.f, 0.f};
      acc1[m][og] = (f32x4){0.f, 0.f, 0.f, 0.f};
    }

  const size_t xcb = (size_t)b * HW * 2 * CIN;
  const int og0 = octile * OG;

  for (int u = tid; u < NROW * 2 * 8; u += 256) {
    int sub = u & 7, rc = u >> 3;
    int pxi = (rc >> 1) * WP + ((rc & 1) ? (W + 1) : 0);
    *(int4*)&Xs[pxi * 64 + ((sub ^ (pxi & 7)) << 3)] = make_int4(0, 0, 0, 0);
  }

  for (int kc = 0; kc < CIN / 32; ++kc) {
    for (int g0 = tid; g0 < NROW * W * 8; g0 += 256) {
      int sub = g0 & 7, px = g0 >> 3;
      int rr = px / W, col = px % W;
      int gr = r0 - 1 + rr;
      int pxi = rr * WP + col + 1;
      int dst = pxi * 64 + ((sub ^ (pxi & 7)) << 3);
      if (gr >= 0 && gr < H) {
        const short* src = XC + xcb + (size_t)(gr * W + col) * 2 * CIN +
                           ((sub & 4) ? CIN : 0) + kc * 32 + (sub & 3) * 8;
        *(int4*)&Xs[dst] = *(const int4*)src;
      } else {
        *(int4*)&Xs[dst] = make_int4(0, 0, 0, 0);
      }
    }
    {
      const short* src = WF + ((size_t)(kc * 9 + 0) * NOGT + og0) * 1024 + tid * (BSH / 256);
      *(int4*)&Bs[0][tid * (BSH / 256)] = *(const int4*)src;
      if constexpr (OG == 4)
        *(int4*)&Bs[0][tid * 16 + 8] = *(const int4*)(src + 8);
    }
    __syncthreads();
#pragma unroll 1
    for (int t = 0; t < 9; ++t) {
      int4 r0v, r1v;
      if (t < 8) {
        const short* src = WF + ((size_t)(kc * 9 + t + 1) * NOGT + og0) * 1024 + tid * (BSH / 256);
        r0v = *(const int4*)src;
        if constexpr (OG == 4) r1v = *(const int4*)(src + 8);
      }
      const short* bs = Bs[t & 1];
      f16x8 bh[OG], bl[OG];
#pragma unroll
      for (int og = 0; og < OG; ++og) {
        bh[og] = *(const f16x8*)&bs[(og * 2 + 0) * 512 + lane * 8];
        bl[og] = *(const f16x8*)&bs[(og * 2 + 1) * 512 + lane * 8];
      }
      const int tp = (t / 3) * WP + (t % 3);
#pragma unroll
      for (int m = 0; m < 5; ++m) {
        int P = Pbase[m] + tp;
        int base = P * 64, ph = P & 7;
        f16x8 ah = *(const f16x8*)&Xs[base + ((kgrp ^ ph) << 3)];
        f16x8 al = *(const f16x8*)&Xs[base + (((kgrp + 4) ^ ph) << 3)];
#pragma unroll
        for (int og = 0; og < OG; ++og) {
          // operand-swapped: W is A, X is B -> C col=px, row=oc
          acc0[m][og] = __builtin_amdgcn_mfma_f32_16x16x32_f16(bh[og], ah, acc0[m][og], 0, 0, 0);
          acc1[m][og] = __builtin_amdgcn_mfma_f32_16x16x32_f16(bl[og], ah, acc1[m][og], 0, 0, 0);
          acc1[m][og] = __builtin_amdgcn_mfma_f32_16x16x32_f16(bh[og], al, acc1[m][og], 0, 0, 0);
        }
      }
      if (t < 8) {
        *(int4*)&Bs[(t + 1) & 1][tid * (BSH / 256)] = r0v;
        if constexpr (OG == 4)
          *(int4*)&Bs[(t + 1) & 1][tid * 16 + 8] = r1v;
      }
      __syncthreads();
    }
  }
  // ---- epilogue: combine, +bias, leaky, f16-split, NHWC store
#pragma unroll
  for (int og = 0; og < OG; ++og) {
    const int oc0 = octile * OG * 16 + og * 16 + kgrp * 4;
    float4 bv = *(const float4*)&bias2[oc0];
#pragma unroll
    for (int m = 0; m < 5; ++m) {
      int px = tile_px0 + wave * 80 + m * 16 + lm;
      if (px < HW) {
        f32x4 v0 = acc0[m][og], v1 = acc1[m][og];
        float o0 = fmaf(v1[0], 4.8828125e-4f, v0[0]) + bv.x;
        float o1 = fmaf(v1[1], 4.8828125e-4f, v0[1]) + bv.y;
        float o2 = fmaf(v1[2], 4.8828125e-4f, v0[2]) + bv.z;
        float o3 = fmaf(v1[3], 4.8828125e-4f, v0[3]) + bv.w;
        o0 = o0 > 0.f ? o0 : 0.1f * o0;
        o1 = o1 > 0.f ? o1 : 0.1f * o1;
        o2 = o2 > 0.f ? o2 : 0.1f * o2;
        o3 = o3 > 0.f ? o3 : 0.1f * o3;
        short h[4], l[4];
        f16_split(o0, h[0], l[0]); f16_split(o1, h[1], l[1]);
        f16_split(o2, h[2], l[2]); f16_split(o3, h[3], l[3]);
        short* d = ACT + ((size_t)(b * HW + px)) * 2 * COUT + oc0;
        uint2 hv, lv;
        hv.x = pk2(h[0], h[1]); hv.y = pk2(h[2], h[3]);
        lv.x = pk2(l[0], l[1]); lv.y = pk2(l[2], l[3]);
        *(uint2*)d = hv;
        *(uint2*)(d + COUT) = lv;
      }
    }
  }
}

// ======== head 1x1 (255 couts) via f16-split MFMA (4-term) + decode ========
// Block 256 = 4 waves; tile 32 px x 256 oc. Wave w: og block w*4..w*4+4.
// GEMM: zero LDS, zero barriers (direct coalesced global frag loads).
template<int CIN>
__global__ __launch_bounds__(256)
void head_mfma_decode(const short* __restrict__ ACT, const short* __restrict__ WH,
                      const float* __restrict__ pb,
                      int HW, int Wl, float strd, int P0,
                      float aw0, float ah0, float aw1, float ah1, float aw2, float ah2,
                      float* __restrict__ out, float* __restrict__ boxes,
                      float* __restrict__ scb, int* __restrict__ clsb) {
  __shared__ float pred[32 * 256];
  const int tid = threadIdx.x, lane = tid & 63, wave = tid >> 6;
  const int lm = lane & 15, kgrp = lane >> 4;
  const int pt = blockIdx.x, b = blockIdx.y;
  const int p0 = pt * 32;
  const int ogb = wave * 4;
  int pxg[2];
#pragma unroll
  for (int m = 0; m < 2; ++m) pxg[m] = min(p0 + m * 16 + lm, HW - 1);
  const short* actb = ACT + (size_t)b * HW * 2 * CIN;
  f32x4 acc0[2][4], acc1[2][4], acc2[2][4];
#pragma unroll
  for (int m = 0; m < 2; ++m)
#pragma unroll
    for (int og = 0; og < 4; ++og) {
      acc0[m][og] = (f32x4){0.f, 0.f, 0.f, 0.f};
      acc1[m][og] = (f32x4){0.f, 0.f, 0.f, 0.f};
      acc2[m][og] = (f32x4){0.f, 0.f, 0.f, 0.f};
    }
#pragma unroll 2
  for (int kc = 0; kc < CIN / 32; ++kc) {
    f16x8 ah[2], al[2], wh[4], wl[4];
#pragma unroll
    for (int m = 0; m < 2; ++m) {
      const short* s = actb + (size_t)pxg[m] * 2 * CIN + kc * 32 + kgrp * 8;
      ah[m] = *(const f16x8*)s;
      al[m] = *(const f16x8*)(s + CIN);
    }
#pragma unroll
    for (int og = 0; og < 4; ++og) {
      const short* s = WH + ((size_t)(kc * 16 + ogb + og) * 2) * 512 + lane * 8;
      wh[og] = *(const f16x8*)s;
      wl[og] = *(const f16x8*)(s + 512);
    }
#pragma unroll
    for (int m = 0; m < 2; ++m)
#pragma unroll
      for (int og = 0; og < 4; ++og) {
        acc0[m][og] = __builtin_amdgcn_mfma_f32_16x16x32_f16(wh[og], ah[m], acc0[m][og], 0, 0, 0);
        acc1[m][og] = __builtin_amdgcn_mfma_f32_16x16x32_f16(wl[og], ah[m], acc1[m][og], 0, 0, 0);
        acc1[m][og] = __builtin_amdgcn_mfma_f32_16x16x32_f16(wh[og], al[m], acc1[m][og], 0, 0, 0);
        acc2[m][og] = __builtin_amdgcn_mfma_f32_16x16x32_f16(wl[og], al[m], acc2[m][og], 0, 0, 0);
      }
  }
  // ---- +pb, write pred tile (fp32, XOR-swizzled granules)
#pragma unroll
  for (int m = 0; m < 2; ++m) {
    const int pxl = m * 16 + lm;
    const int swz = pxl & 28;
#pragma unroll
    for (int og = 0; og < 4; ++og) {
      const int ch0 = (ogb + og) * 16 + kgrp * 4;
      float4 v;
      const float c = 4.8828125e-4f;
#pragma unroll
      for (int j = 0; j < 4; ++j) {
        float pbv = (ch0 + j < 255) ? pb[ch0 + j] : 0.f;
        float t = fmaf(acc2[m][og][j], c, acc1[m][og][j]);
        (&v.x)[j] = fmaf(t, c, acc0[m][og][j]) + pbv;
      }
      *(float4*)&pred[pxl * 256 + (ch0 ^ swz)] = v;
    }
  }
  __syncthreads();
  // ---- decode: 96 threads = 32 px x 3 anchors
  if (tid < 96) {
    const int px = tid & 31, a = tid >> 5;
    const int p = p0 + px;
    if (p < HW) {
      const int swz = px & 28;
      const float* pr = &pred[px * 256];
#define RD(ch) pr[(ch) ^ swz]
      float conf = RD(a);
      int ch0 = 3 + 80 * a;
      float m = -1e30f; int ci = 0;
      for (int i = 0; i < 80; ++i) {
        float v = RD(ch0 + i);
        if (v > m) { m = v; ci = i; }
      }
      float ssum = 0.f;
      for (int i = 0; i < 80; ++i) ssum += expf(RD(ch0 + i) - m);
      float sig = 1.f / (1.f + expf(-conf));
      float sc = sig / ssum;
      float tx = RD(243 + 4 * a), ty = RD(244 + 4 * a);
      float tw = RD(245 + 4 * a), th = RD(246 + 4 * a);
#undef RD
      float gxx = (float)(p % Wl), gy = (float)(p / Wl);
      float aw = (a == 0) ? aw0 : ((a == 1) ? aw1 : aw2);
      float ah = (a == 0) ? ah0 : ((a == 1) ? ah1 : ah2);
      float cx = (1.f / (1.f + expf(-tx)) + gxx) * strd;
      float cy2 = (1.f / (1.f + expf(-ty)) + gy) * strd;
      float bw = expf(tw) * aw, bh = expf(th) * ah;
      float x1 = fminf(fmaxf((cx - bw * 0.5f) / 640.f, 0.f), 1.f);
      float y1 = fminf(fmaxf((cy2 - bh * 0.5f) / 640.f, 0.f), 1.f);
      float x2 = fminf(fmaxf((cx + bw * 0.5f) / 640.f, 0.f), 1.f);
      float y2 = fminf(fmaxf((cy2 + bh * 0.5f) / 640.f, 0.f), 1.f);
      int n = (P0 + p) * 3 + a;
      size_t gg = (size_t)b * 25200 + n;
      out[gg * 5 + 0] = (x1 + x2) * 0.5f * 640.f;
      out[gg * 5 + 1] = (y1 + y2) * 0.5f * 640.f;
      out[gg * 5 + 2] = (x2 - x1) * 640.f;
      out[gg * 5 + 3] = (y2 - y1) * 640.f;
      out[gg * 5 + 4] = sc;
      out[(size_t)8 * 25200 * 5 + gg] = (float)ci;
      out[(size_t)8 * 25200 * 6 + gg] = 0.f;
      boxes[gg * 4 + 0] = x1; boxes[gg * 4 + 1] = y1;
      boxes[gg * 4 + 2] = x2; boxes[gg * 4 + 3] = y2;
      scb[gg] = sc; clsb[gg] = ci;
    }
  }
}

// ================= top-k (compact + bitonic) =================
__global__ __launch_bounds__(256)
void topk_sort(const float* __restrict__ scb, const float* __restrict__ boxes,
               const int* __restrict__ clsb,
               int* __restrict__ tidx, int* __restrict__ tval, float* __restrict__ tbox) {
  __shared__ ull keys[4096];
  __shared__ int cnt;
  const int b = blockIdx.x, tid = threadIdx.x;
  if (tid == 0) cnt = 0;
  __syncthreads();
  for (int n = tid; n < 25200; n += 256) {
    float s = scb[(size_t)b * 25200 + n];
    if (s >= 0.3f) {
      int p = atomicAdd(&cnt, 1);
      if (p < 4096)
        keys[p] = ((ull)__float_as_uint(s) << 32) | (ull)(0xFFFFFFFFu - (unsigned)n);
    }
  }
  __syncthreads();
  int c = min(cnt, 4096);
  int P2 = 1024;
  while (P2 < c) P2 <<= 1;
  for (int i = c + tid; i < P2; i += 256) keys[i] = 0ull;
  __syncthreads();
  for (int len = 2; len <= P2; len <<= 1) {
    for (int j = len >> 1; j > 0; j >>= 1) {
      for (int x = tid; x < P2; x += 256) {
        int y = x ^ j;
        if (y > x) {
          ull a = keys[x], bb = keys[y];
          bool up = (x & len) == 0;
          if (up ? (a < bb) : (a > bb)) { keys[x] = bb; keys[y] = a; }
        }
      }
      __syncthreads();
    }
  }
  for (int i = tid; i < 1000; i += 256) {
    ull k = keys[i];
    int valid = (k != 0ull) ? 1 : 0;
    int n = valid ? (int)(0xFFFFFFFFu - (unsigned)(k & 0xFFFFFFFFull)) : 0;
    float cls = (float)clsb[(size_t)b * 25200 + n];
    float off = cls * 4.0f;
    const float* bp = &boxes[((size_t)b * 25200 + n) * 4];
    tidx[b * 1000 + i] = n;
    tval[b * 1000 + i] = valid;
    tbox[(b * 1000 + i) * 4 + 0] = bp[0] + off;
    tbox[(b * 1000 + i) * 4 + 1] = bp[1] + off;
    tbox[(b * 1000 + i) * 4 + 2] = bp[2] + off;
    tbox[(b * 1000 + i) * 4 + 3] = bp[3] + off;
  }
}

// ====== pairwise suppression bitmasks: grid (16 j-chunks, 8 batches) ======
// Each block: 64 j-boxes staged in LDS; thread i computes one 64-bit word.
__global__ __launch_bounds__(1024)
void supmask(const float* __restrict__ tbox, ull* __restrict__ sup) {
  __shared__ float4 bj[64];
  __shared__ float arj[64];
  const int jc = blockIdx.x, b = blockIdx.y;
  const int tid = threadIdx.x;
  if (tid < 64) {
    int j = min(jc * 64 + tid, 999);   // clamp: spurious bits land in word-15
    float4 v = *(const float4*)&tbox[((size_t)b * 1000 + j) * 4];
    bj[tid] = v;                       // positions >=40, never set in keepw
    arj[tid] = (v.z - v.x) * (v.w - v.y);
  }
  __syncthreads();
  if (tid < 1000) {
    float4 bi = *(const float4*)&tbox[((size_t)b * 1000 + tid) * 4];
    float ai = (bi.z - bi.x) * (bi.w - bi.y);
    ull w = 0;
#pragma unroll 8
    for (int j = 0; j < 64; ++j) {
      float4 bv = bj[j];
      float xx1 = fmaxf(bi.x, bv.x), yy1 = fmaxf(bi.y, bv.y);
      float xx2 = fminf(bi.z, bv.z), yy2 = fminf(bi.w, bv.w);
      float inter = fmaxf(1e-28f, xx2 - xx1) * fmaxf(1e-28f, yy2 - yy1);
      float iou = inter / (ai + arj[j] - inter);
      if (iou > 0.5f) w |= 1ull << j;
    }
    sup[((size_t)b * 1000 + tid) * 16 + jc] = w;
  }
}

// ====== greedy NMS: bit-parallel scan, visits only live candidates ======
// lane l<16 holds removed-word l in a register. Per 64-chunk:
//   w = valid & ~removed[c]; while(w): i=ctz(w); keep i;
//   removed_l |= suprow[i][l] (coalesced 128B); w &= ~suprow[i][c] (broadcast).
// Equivalent to reference greedy (sup symmetric; self-bit clears after keep).
__global__ __launch_bounds__(64)
void nms_kernel(const ull* __restrict__ sup, const int* __restrict__ tval,
                const int* __restrict__ tidx, float* __restrict__ keep_out) {
  const int b = blockIdx.x, lane = threadIdx.x;
  const ull* supb = sup + (size_t)b * 16000;
  ull removed = 0;     // lane l<16: removed word l
  for (int c = 0; c < 16; ++c) {
    const int i0 = c * 64;
    const int nIn = min(64, 1000 - i0);
    int myvalid = (lane < nIn) ? tval[b * 1000 + i0 + lane] : 0;
    int myidx = (lane < nIn) ? tidx[b * 1000 + i0 + lane] : 0;
    ull w = __ballot(myvalid != 0) & ~__shfl(removed, c);
    while (w) {
      int il = __ffsll((long long)w) - 1;
      int i = i0 + il;
      ull row_l = (lane < 16) ? supb[(size_t)i * 16 + lane] : 0ull;  // 128B coalesced
      ull row_c = supb[(size_t)i * 16 + c];    // wave-uniform -> broadcast load
      if (lane == il) keep_out[(size_t)b * 25200 + myidx] = 1.0f;
      removed |= row_l;
      w &= ~row_c;            // drop items suppressed by i (incl. self-bit)
      w &= ~(1ull << il);
    }
  }
}

// ================= launch =================
extern "C" void kernel_launch(void* const* d_in, const int* in_sizes, int n_in,
                              void* d_out, int out_size, void* d_ws, size_t ws_size,
                              hipStream_t stream) {
  const float* p3 = (const float*)d_in[0];
  const float* p4 = (const float*)d_in[1];
  const float* p5 = (const float*)d_in[2];
  auto L = [&](int lvl, int k) { return (const float*)d_in[3 + lvl * 8 + k]; };
  float* out = (float*)d_out;
  char* ws = (char*)d_ws;
  size_t o = 0;
  short* ACT = (short*)(ws + o);   o += (size_t)26214400 * 2;   // NHWC f16 hi/lo
  short* XC  = (short*)(ws + o);   o += (size_t)13107200 * 2;
  short* WF  = (short*)(ws + o);   o += (size_t)9437184 * 2;
  float* bias2 = (float*)(ws + o); o += 2048 * 4;
  float* boxes = (float*)(ws + o); o += (size_t)806400 * 4;
  float* scb = (float*)(ws + o);   o += (size_t)201600 * 4;
  int* clsb = (int*)(ws + o);      o += (size_t)201600 * 4;
  int* tidx = (int*)(ws + o);      o += 8000 * 4;
  int* tval = (int*)(ws + o);      o += 8000 * 4;
  float* tbox = (float*)(ws + o);  o += 32000 * 4;
  ull* sup = (ull*)(ws + o);       o += (size_t)128000 * 8;
  // WH overlays XC tail (hwprep runs after conv consumed XC; xprep of next
  // level runs after head consumed WH -- stream-ordered, no hazard)
  short* WH = XC + (13107200 - 524288);
  float* b2_1 = bias2, *b2_2 = bias2 + 256, *b2_3 = bias2 + 768;

  bfold<<<1, 256, 0, stream>>>(L(0, 1), L(0, 2), L(0, 3), L(0, 4), L(0, 5), b2_1, 256);
  bfold<<<2, 256, 0, stream>>>(L(1, 1), L(1, 2), L(1, 3), L(1, 4), L(1, 5), b2_2, 512);
  bfold<<<4, 256, 0, stream>>>(L(2, 1), L(2, 2), L(2, 3), L(2, 4), L(2, 5), b2_3, 1024);

  // ---- level 1: 128->256, 80x80
  wprep<<<144, 256, 0, stream>>>(L(0, 0), L(0, 2), L(0, 5), WF, 128, 4);
  xprep<<<dim3(50, 4, 8), 256, 0, stream>>>(p3, XC, 6400, 128);
  conv3x3_mfma<128, 256, 80, 80, 4, 4><<<dim3(20, 4, 8), 256, 0, stream>>>(XC, WF, b2_1, ACT);
  hwprep<<<32, 256, 0, stream>>>(L(0, 6), WH, 256);
  head_mfma_decode<256><<<dim3(200, 8), 256, 0, stream>>>(
      ACT, WH, L(0, 7), 6400, 80, 8.f, 0,
      32.64f, 47.68f, 50.24f, 108.16f, 126.72f, 96.32f, out, boxes, scb, clsb);
  // ---- level 2: 256->512, 40x40
  wprep<<<576, 256, 0, stream>>>(L(1, 0), L(1, 2), L(1, 5), WF, 256, 5);
  xprep<<<dim3(13, 8, 8), 256, 0, stream>>>(p4, XC, 1600, 256);
  conv3x3_mfma<256, 512, 40, 40, 8, 4><<<dim3(5, 8, 8), 256, 0, stream>>>(XC, WF, b2_2, ACT);
  hwprep<<<64, 256, 0, stream>>>(L(1, 6), WH, 512);
  head_mfma_decode<512><<<dim3(50, 8), 256, 0, stream>>>(
      ACT, WH, L(1, 7), 1600, 40, 16.f, 6400,
      78.4f, 201.92f, 178.24f, 178.56f, 129.6f, 294.72f, out, boxes, scb, clsb);
  // ---- level 3: 512->1024, 20x20
  wprep<<<2304, 256, 0, stream>>>(L(2, 0), L(2, 2), L(2, 5), WF, 512, 6);
  xprep<<<dim3(4, 16, 8), 256, 0, stream>>>(p5, XC, 400, 512);
  conv3x3_mfma<512, 1024, 20, 20, 16, 2><<<dim3(2, 32, 8), 256, 0, stream>>>(XC, WF, b2_3, ACT);
  hwprep<<<128, 256, 0, stream>>>(L(2, 6), WH, 1024);
  head_mfma_decode<1024><<<dim3(13, 8), 256, 0, stream>>>(
      ACT, WH, L(2, 7), 400, 20, 32.f, 8000,
      331.84f, 194.56f, 227.84f, 325.76f, 365.44f, 358.72f, out, boxes, scb, clsb);
  // ---- NMS pipeline
  topk_sort<<<8, 256, 0, stream>>>(scb, boxes, clsb, tidx, tval, tbox);
  supmask<<<dim3(16, 8), 1024, 0, stream>>>(tbox, sup);
  nms_kernel<<<8, 64, 0, stream>>>(sup, tval, tidx, out + (size_t)8 * 25200 * 6);
}